// Round 16
// baseline (170.788 us; speedup 1.0000x reference)
//
#include <hip/hip_runtime.h>
#include <hip/hip_bf16.h>
#include <math.h>

#define N_ROWS 16384      // 8 * 2048
#define DIM    256
#define KCODES 8192

// Output layout (float offsets), reference return order
#define OFF_ZQ    0
#define OFF_CODES 4194304
#define OFF_LOSS  4210688
#define OFF_CB    4210689
#define OFF_CS    6307841
#define OFF_EW    6316033
#define OUT_TOTAL 8413185

typedef __attribute__((ext_vector_type(8))) short bf16x8;
typedef __attribute__((ext_vector_type(4))) float f32x4;
typedef __attribute__((ext_vector_type(16))) float f32x16;

__device__ __forceinline__ void gll16(const void* g, void* l) {
  __builtin_amdgcn_global_load_lds(
      (const __attribute__((address_space(1))) unsigned int*)g,
      (__attribute__((address_space(3))) unsigned int*)l, 16, 0, 0);
}

__device__ __forceinline__ unsigned short f2bf(float x) {
  __hip_bfloat16 h = __float2bfloat16(x);
  return *reinterpret_cast<unsigned short*>(&h);
}

__device__ __forceinline__ unsigned umin32(unsigned a, unsigned b) { return a < b ? a : b; }
__device__ __forceinline__ unsigned umax32(unsigned a, unsigned b) { return a > b ? a : b; }

// --- fused prep: z->bf16, cb->transposed bf16(-2c)+norms, zero cnt/loss ---
__global__ __launch_bounds__(256) void k_pre(
    const float* __restrict__ z, unsigned short* __restrict__ zbuf,
    const float* __restrict__ cb, unsigned short* __restrict__ cbt,
    float* __restrict__ cnormb, int* __restrict__ cnt,
    float* __restrict__ loss_part) {
  const int b = blockIdx.x;
  const int tid = threadIdx.x;
  if (b < 2048) {                      // z convert (8 elems/thread)
    int i = b * 256 + tid;
    const float4 a = ((const float4*)z)[i * 2];
    const float4 c = ((const float4*)z)[i * 2 + 1];
    union { unsigned short u[8]; uint4 v; } o;
    o.u[0] = f2bf(a.x); o.u[1] = f2bf(a.y); o.u[2] = f2bf(a.z); o.u[3] = f2bf(a.w);
    o.u[4] = f2bf(c.x); o.u[5] = f2bf(c.y); o.u[6] = f2bf(c.z); o.u[7] = f2bf(c.w);
    ((uint4*)zbuf)[i] = o.v;
  } else if (b < 3072) {               // cb transpose + biased norms
    const int code = (b - 2048) * 8 + (tid >> 5);
    const int dq = tid & 31;
    const float4 v0 = *(const float4*)(cb + (size_t)code * 256 + dq * 8);
    const float4 v1 = *(const float4*)(cb + (size_t)code * 256 + dq * 8 + 4);
    union { unsigned short u[8]; uint4 q; } o;
    o.u[0] = f2bf(-2.f * v0.x); o.u[1] = f2bf(-2.f * v0.y);
    o.u[2] = f2bf(-2.f * v0.z); o.u[3] = f2bf(-2.f * v0.w);
    o.u[4] = f2bf(-2.f * v1.x); o.u[5] = f2bf(-2.f * v1.y);
    o.u[6] = f2bf(-2.f * v1.z); o.u[7] = f2bf(-2.f * v1.w);
    *(uint4*)(cbt + ((size_t)dq * 8192 + code) * 8) = o.q;
    float s = v0.x * v0.x + v0.y * v0.y + v0.z * v0.z + v0.w * v0.w +
              v1.x * v1.x + v1.y * v1.y + v1.z * v1.z + v1.w * v1.w;
#pragma unroll
    for (int off = 16; off >= 1; off >>= 1) s += __shfl_down(s, off);
    if ((tid & 31) == 0) cnormb[code] = s + 1024.0f;   // bias baked in
  } else if (cnt) {                    // zero accumulators
    int zi = (b - 3072) * 256 + tid;
    if (zi < 8192) cnt[zi] = 0;
    else if (zi < 8448) loss_part[zi - 8192] = 0.0f;
  }
}

// ---------------- persistent-z MFMA argmin (32x32x16) --------------------
// R8 schedule; block = 64 rows x 1024 codes (half the R8 row tile) so the
// per-wave register footprint (~64 VGPR zr + 32 AGPR acc) fits 3-4 waves/SIMD
// instead of 2 -- occupancy was register-limited, not LDS-limited (R15).
__global__ __launch_bounds__(256, 2) void k_argmin(
    const unsigned short* __restrict__ zb,   // [16384][256] bf16 row-major
    const unsigned short* __restrict__ cbt,  // [32 dq][8192 codes] bf16 of -2c
    const float* __restrict__ cnb,           // [8192] ||c||^2 + 1024
    unsigned long long* __restrict__ partials) {  // [16384 row][32 entry]
  __shared__ __align__(16) unsigned char lds[20480]; // 16K z-phase/cb + 4K cnorm

  const int tid = threadIdx.x;
  const int lane = tid & 63;
  const int w = tid >> 6;
  const int wc = w & 1;
  const int wr = w >> 1;
  const int hi = lane >> 5;
  const int l31 = lane & 31;
  const int chunk = blockIdx.x;      // [0,8): 1024 codes per block
  const int r0 = blockIdx.y << 6;    // row tile (64 rows)

  // ---- prologue: cnorm chunk + z in 2 phases of 32 rows through 16KB ----
  gll16((const char*)cnb + (size_t)chunk * 4096 + tid * 16,
        lds + 16384 + tid * 16);
  const char* zgb = (const char*)zb + (size_t)r0 * 512;
#pragma unroll
  for (int it = 0; it < 4; ++it) {   // phase 0 staging (rows 0-31)
    int s = it * 256 + tid;
    int row = s >> 5;
    int dql = (s & 31) ^ row;
    gll16(zgb + row * 512 + dql * 16, lds + s * 16);
  }

  bf16x8 zr0[16];
#pragma unroll
  for (int p = 0; p < 2; ++p) {
    asm volatile("s_waitcnt vmcnt(0)" ::: "memory");
    __builtin_amdgcn_s_barrier();
    __builtin_amdgcn_sched_barrier(0);
    if (p == wr) {   // phase p holds rows [p*32, p*32+32)
      const int xr = l31 * 16;
      const int rb = l31 * 512;
      const int hx = hi * 16;
#pragma unroll
      for (int ks = 0; ks < 16; ++ks)
        zr0[ks] = *(const bf16x8*)(lds + rb + ((ks * 32 + hx) ^ xr));
    }
    asm volatile("s_waitcnt lgkmcnt(0)" ::: "memory");
    __builtin_amdgcn_sched_barrier(0);
    __builtin_amdgcn_s_barrier();
    if (p < 1) {   // stage phase 1 (rows 32-63) into same 16KB
#pragma unroll
      for (int it = 0; it < 4; ++it) {
        int s = it * 256 + tid;
        int row = s >> 5;
        int dql = (s & 31) ^ row;
        gll16(zgb + (32 + row) * 512 + dql * 16, lds + s * 16);
      }
    }
  }

  // ---- cb staging setup; prologue stages g=0,1,2 (slots reuse z buffer) ----
  unsigned char* lcb = lds + tid * 16;
  const char* cgc = (const char*)cbt +
      ((size_t)(tid >> 7) * 131072 + (size_t)chunk * 16384 + (tid & 127) * 16);
  gll16(cgc + 0 * 262144, lcb + 0 * 4096);
  gll16(cgc + 1 * 262144, lcb + 1 * 4096);
  gll16(cgc + 2 * 262144, lcb + 2 * 4096);

  const unsigned char* afp = lds + hi * 2048 + (wc * 64 + l31) * 16;
  const unsigned wchi4 = (unsigned)(wc * 64 + hi * 4);

  unsigned k1_00 = 0xFFFFFFFFu, k2_00 = 0xFFFFFFFFu;
  unsigned k1_10 = 0xFFFFFFFFu, k2_10 = 0xFFFFFFFFu;
  f32x16 acc00, acc10;

#define KSTEP(ks, TAIL)                                                        \
  {                                                                            \
    if ((TAIL) && (ks) == 14) asm volatile("s_waitcnt vmcnt(1)" ::: "memory"); \
    else if ((TAIL) && (ks) == 15) asm volatile("s_waitcnt vmcnt(0)" ::: "memory"); \
    else asm volatile("s_waitcnt vmcnt(2)" ::: "memory");                      \
    __builtin_amdgcn_s_barrier();                                              \
    __builtin_amdgcn_sched_barrier(0);                                         \
    if ((ks) < 13) {                                                           \
      gll16(cgc + ((ks) + 3) * 262144, lcb + (((ks) + 3) & 3) * 4096);         \
    } else if (!(TAIL)) {                                                      \
      gll16(cgc + 2048 + ((ks) - 13) * 262144, lcb + (((ks) + 3) & 3) * 4096); \
    }                                                                          \
    bf16x8 a0 = *(const bf16x8*)(afp + ((ks) & 3) * 4096);                     \
    bf16x8 a1 = *(const bf16x8*)(afp + ((ks) & 3) * 4096 + 512);               \
    acc00 = __builtin_amdgcn_mfma_f32_32x32x16_bf16(a0, zr0[ks], acc00, 0, 0, 0); \
    acc10 = __builtin_amdgcn_mfma_f32_32x32x16_bf16(a1, zr0[ks], acc10, 0, 0, 0); \
  }

// branchless top-2 merge: exact same result as the if-chain (keys unique)
#define MRG(K1V, K2V, KEY)                                                     \
  {                                                                            \
    unsigned t_ = umax32(K1V, (KEY));                                          \
    K2V = umin32(K2V, t_);                                                     \
    K1V = umin32(K1V, (KEY));                                                  \
  }

#define CTBODY(TAIL)                                                           \
  {                                                                            \
    const int cnoff = 16384 + ct * 512 + wc * 256 + hi * 16;                   \
    f32x4 cnA[4], cnB[4];                                                      \
    _Pragma("unroll") for (int g2 = 0; g2 < 4; ++g2) {                         \
      cnA[g2] = *(const f32x4*)(lds + cnoff + g2 * 32);                        \
      cnB[g2] = *(const f32x4*)(lds + cnoff + 128 + g2 * 32);                  \
    }                                                                          \
    _Pragma("unroll") for (int r = 0; r < 16; ++r) {                           \
      acc00[r] = cnA[r >> 2][r & 3];                                           \
      acc10[r] = cnB[r >> 2][r & 3];                                           \
    }                                                                          \
    KSTEP(0, TAIL)  KSTEP(1, TAIL)  KSTEP(2, TAIL)  KSTEP(3, TAIL)             \
    KSTEP(4, TAIL)  KSTEP(5, TAIL)  KSTEP(6, TAIL)  KSTEP(7, TAIL)             \
    KSTEP(8, TAIL)  KSTEP(9, TAIL)  KSTEP(10, TAIL) KSTEP(11, TAIL)            \
    KSTEP(12, TAIL) KSTEP(13, TAIL) KSTEP(14, TAIL) KSTEP(15, TAIL)            \
    const unsigned vb = (unsigned)(ct * 128) | wchi4;                          \
    _Pragma("unroll") for (int r = 0; r < 16; ++r) {                           \
      const unsigned base = (unsigned)(8 * (r >> 2) + (r & 3));                \
      unsigned key;                                                            \
      key = (__float_as_uint(acc00[r]) & 0xFFFFFC00u) | (vb | base);           \
      MRG(k1_00, k2_00, key)                                                   \
      key = (__float_as_uint(acc10[r]) & 0xFFFFFC00u) | (vb | base | 32u);     \
      MRG(k1_10, k2_10, key)                                                   \
    }                                                                          \
    cgc += 2048;                                                               \
  }

  for (int ct = 0; ct < 7; ++ct) CTBODY(false)
  { int ct = 7; CTBODY(true) }
#undef CTBODY
#undef MRG
#undef KSTEP

  // ---- final: merge lane <-> lane+32, store per-cf top-2 ----
#define FIN(K1V, K2V, CF)                                                      \
  {                                                                            \
    unsigned o1 = (unsigned)__shfl_xor((int)(K1V), 32);                        \
    unsigned o2 = (unsigned)__shfl_xor((int)(K2V), 32);                        \
    unsigned n1 = umin32((K1V), o1);                                           \
    unsigned n2 = umin32(umax32((K1V), o1), umin32((K2V), o2));                \
    if (lane < 32) {                                                           \
      int row = r0 + wr * 32 + l31;                                            \
      partials[(size_t)row * 32 + (chunk * 4 + wc * 2 + (CF))] =               \
          ((unsigned long long)n2 << 32) | n1;                                 \
    }                                                                          \
  }
  FIN(k1_00, k2_00, 0) FIN(k1_10, k2_10, 1)
#undef FIN
}

// -------- merge partials (wave per row) + exact refine + histogram --------
__global__ __launch_bounds__(256) void k_reduce(
    const unsigned long long* __restrict__ partials, const float* __restrict__ z,
    const float* __restrict__ cb, float* __restrict__ out_codes,
    int* __restrict__ cnt) {
  const int row = blockIdx.x * 4 + (threadIdx.x >> 6);
  const int lane = threadIdx.x & 63;
  const int e = lane & 31;

  unsigned myK1 = 0xFFFFFFFFu, myK2 = 0xFFFFFFFFu;
  if (lane < 32) {
    unsigned long long v = partials[(size_t)row * 32 + e];
    myK1 = (unsigned)v; myK2 = (unsigned)(v >> 32);
  }
  unsigned K1 = myK1, K2 = myK2;
  int bc = e >> 2;   // 1024-code chunk of K1
#pragma unroll
  for (int m = 1; m <= 32; m <<= 1) {
    unsigned o1 = (unsigned)__shfl_xor((int)K1, m);
    unsigned o2 = (unsigned)__shfl_xor((int)K2, m);
    int ob = __shfl_xor(bc, m);
    unsigned nK2 = umin32(umax32(K1, o1), umin32(K2, o2));
    if (o1 < K1 || (o1 == K1 && ob < bc)) { K1 = o1; bc = ob; }
    K2 = nK2;
  }
  int chosen = bc * 1024 + (int)(K1 & 1023u);

  float r1 = __uint_as_float(K1 & 0xFFFFFC00u);
  float r2 = __uint_as_float(K2 & 0xFFFFFC00u);
  if (r2 - r1 < 0.75f) {   // wave-uniform near-tie: exact fp64 re-eval
    const float win = r1 + 0.75f;
    const float* zr = z + ((size_t)row << 8);
    double bestd = 1e300; int bestj = 0x7fffffff;
#pragma unroll
    for (int h = 0; h < 2; ++h) {
      unsigned k = h ? myK2 : myK1;
      float bv = __uint_as_float(k & 0xFFFFFC00u);
      if (lane < 32 && bv <= win) {
        int jv = (e >> 2) * 1024 + (int)(k & 1023u);
        const float* c = cb + ((size_t)jv << 8);
        double d = 0.0;
        for (int kk = 0; kk < DIM; ++kk) {
          double df = (double)zr[kk] - (double)c[kk];
          d += df * df;
        }
        if (d < bestd || (d == bestd && jv < bestj)) { bestd = d; bestj = jv; }
      }
    }
#pragma unroll
    for (int m = 1; m <= 32; m <<= 1) {
      double od = __shfl_xor(bestd, m);
      int oj = __shfl_xor(bestj, m);
      if (od < bestd || (od == bestd && oj < bestj)) { bestd = od; bestj = oj; }
    }
    chosen = bestj;
  }
  if (lane == 0) {
    out_codes[row] = (float)chosen;
    if (cnt) atomicAdd(&cnt[chosen], 1);
  }
}

// ---- fused scan + place: 1 block, shuffle prefix + LDS cursors -----------
__global__ __launch_bounds__(1024) void k_scanplace(
    const int* __restrict__ cnt, int* __restrict__ start,
    const float* __restrict__ ema_cs, float* __restrict__ cs_out,
    const float* __restrict__ codesf, int* __restrict__ rowlist) {
  __shared__ int lcur[8192];
  __shared__ int wsum[16], wbase[16];
  const int t = threadIdx.x;
  const int lane = t & 63, wid = t >> 6;
  const int base = t * 8;
  int c[8], s = 0;
#pragma unroll
  for (int i = 0; i < 8; ++i) { c[i] = cnt[base + i]; s += c[i]; }
  int inc = s;
#pragma unroll
  for (int off = 1; off < 64; off <<= 1) {
    int v = __shfl_up(inc, off);
    if (lane >= off) inc += v;
  }
  if (lane == 63) wsum[wid] = inc;
  __syncthreads();
  if (t < 16) {
    int v = wsum[t];
    int winc = v;
#pragma unroll
    for (int off = 1; off < 16; off <<= 1) {
      int u = __shfl_up(winc, off);
      if (t >= off) winc += u;
    }
    wbase[t] = winc - v;
  }
  __syncthreads();
  int ex = wbase[wid] + (inc - s);
#pragma unroll
  for (int i = 0; i < 8; ++i) {
    start[base + i] = ex;
    lcur[base + i] = ex;
    cs_out[base + i] = 0.99f * ema_cs[base + i] + 0.01f * (float)c[i];
    ex += c[i];
  }
  __syncthreads();
#pragma unroll
  for (int rr = 0; rr < 16; ++rr) {
    int r = rr * 1024 + t;
    int cc = (int)codesf[r];
    int p = atomicAdd(&lcur[cc], 1);
    rowlist[p] = r;
  }
}

// fused per-code pass: z_q gather-write + dw sum + EMA + codebook + loss
__global__ __launch_bounds__(256) void k_dw2(
    const float* __restrict__ z, const float* __restrict__ cb,
    const int* __restrict__ start, const int* __restrict__ cnt,
    const int* __restrict__ rowlist, const float* __restrict__ ema_w,
    const float* __restrict__ cs_new, float* __restrict__ zq,
    float* __restrict__ ew, float* __restrict__ cb_out,
    float* __restrict__ loss_part) {
  const int k = blockIdx.x;
  const int d = threadIdx.x;
  const int s = start[k], n = cnt[k];
  const size_t o = ((size_t)k << 8) + d;
  const float q = cb[o];
  float a0 = 0.f, a1 = 0.f, a2 = 0.f, a3 = 0.f;
  float l0 = 0.f, l1 = 0.f, l2 = 0.f, l3 = 0.f;
  int t = 0;
  for (; t + 4 <= n; t += 4) {
    size_t ro0 = ((size_t)rowlist[s + t] << 8) + d;
    size_t ro1 = ((size_t)rowlist[s + t + 1] << 8) + d;
    size_t ro2 = ((size_t)rowlist[s + t + 2] << 8) + d;
    size_t ro3 = ((size_t)rowlist[s + t + 3] << 8) + d;
    float z0 = z[ro0], z1 = z[ro1], z2 = z[ro2], z3 = z[ro3];
    zq[ro0] = q; zq[ro1] = q; zq[ro2] = q; zq[ro3] = q;
    a0 += z0; a1 += z1; a2 += z2; a3 += z3;
    float d0 = z0 - q, d1 = z1 - q, d2 = z2 - q, d3 = z3 - q;
    l0 += d0 * d0; l1 += d1 * d1; l2 += d2 * d2; l3 += d3 * d3;
  }
  for (; t < n; ++t) {
    size_t ro = ((size_t)rowlist[s + t] << 8) + d;
    float zv = z[ro];
    zq[ro] = q;
    a0 += zv;
    float df = zv - q;
    l0 += df * df;
  }
  float a = (a0 + a1) + (a2 + a3);
  float lacc = (l0 + l1) + (l2 + l3);
  const float v = 0.99f * ema_w[o] + 0.01f * a;
  ew[o] = v;
  cb_out[o] = v / (cs_new[k] + 1e-5f);

#pragma unroll
  for (int off = 32; off >= 1; off >>= 1) lacc += __shfl_down(lacc, off);
  __shared__ float wp[4];
  if ((d & 63) == 0) wp[d >> 6] = lacc;
  __syncthreads();
  if (d == 0 && n > 0) {
    float ssum = (wp[0] + wp[1]) + (wp[2] + wp[3]);
    atomicAdd(loss_part + (k & 255), ssum * (float)(0.1 / 4194304.0));
  }
}

__global__ __launch_bounds__(256) void k_loss_final(
    const float* __restrict__ part, float* __restrict__ loss) {
  float s = part[threadIdx.x];
#pragma unroll
  for (int off = 32; off >= 1; off >>= 1) s += __shfl_down(s, off);
  __shared__ float w[4];
  if ((threadIdx.x & 63) == 0) w[threadIdx.x >> 6] = s;
  __syncthreads();
  if (threadIdx.x == 0) loss[0] = (w[0] + w[1]) + (w[2] + w[3]);
}

// ---------------- fallback atomic path (ws too small) ---------------------
__global__ __launch_bounds__(256) void k_scatter(
    const float* __restrict__ z, const float* __restrict__ cb,
    const float* __restrict__ codesf, float* __restrict__ zq,
    float* __restrict__ loss, float* __restrict__ cs_acc,
    float* __restrict__ ew_acc) {
  const int row = blockIdx.x;
  const int d = threadIdx.x;
  const int c = (int)codesf[row];
  const float zv = z[((size_t)row << 8) + d];
  const float qv = cb[((size_t)c << 8) + d];
  zq[((size_t)row << 8) + d] = zv + (qv - zv);
  float diff = zv - qv;
  float sq = diff * diff;
#pragma unroll
  for (int off = 32; off >= 1; off >>= 1) sq += __shfl_down(sq, off);
  __shared__ float wpart[4];
  if ((d & 63) == 0) wpart[d >> 6] = sq;
  __syncthreads();
  if (d == 0) {
    float s = (wpart[0] + wpart[1]) + (wpart[2] + wpart[3]);
    atomicAdd(loss, s * (float)(0.1 / 4194304.0));
    atomicAdd(cs_acc + c, 1.0f);
  }
  atomicAdd(ew_acc + ((size_t)c << 8) + d, zv);
}

__global__ __launch_bounds__(256) void k_ema_cs(const float* __restrict__ ema_cs,
                                                float* __restrict__ cs_io) {
  const int k = blockIdx.x * 256 + threadIdx.x;
  const float cnt = cs_io[k];
  cs_io[k] = 0.99f * ema_cs[k] + 0.01f * cnt;
}

__global__ __launch_bounds__(256) void k_ema_w(const float* __restrict__ ema_w,
                                               const float* __restrict__ cs_new,
                                               float* __restrict__ ew_io,
                                               float* __restrict__ cb_out) {
  const int i = blockIdx.x * 256 + threadIdx.x;
  const float dw = ew_io[i];
  const float v = 0.99f * ema_w[i] + 0.01f * dw;
  ew_io[i] = v;
  cb_out[i] = v / (cs_new[i >> 8] + 1e-5f);
}

// ---------------- launch --------------------------------------------------
extern "C" void kernel_launch(void* const* d_in, const int* in_sizes, int n_in,
                              void* d_out, int out_size, void* d_ws, size_t ws_size,
                              hipStream_t stream) {
  const float* z      = (const float*)d_in[0];
  const float* cb     = (const float*)d_in[1];
  const float* ema_cs = (const float*)d_in[2];
  const float* ema_w  = (const float*)d_in[3];
  float* out = (float*)d_out;

  float* o_zq    = out + OFF_ZQ;
  float* o_codes = out + OFF_CODES;
  float* o_loss  = out + OFF_LOSS;
  float* o_cb    = out + OFF_CB;
  float* o_cs    = out + OFF_CS;
  float* o_ew    = out + OFF_EW;

  // scratch aliases inside output regions (each overwritten later in order):
  //   z_bf16 (8.39MB)                        -> o_cb region
  //   cbt transposed (4.19MB) + cnormb (32K) -> o_ew region
  //   partials (4MB)                         -> o_zq region
  uintptr_t zb_a  = ((uintptr_t)o_cb + 15) & ~(uintptr_t)15;
  uintptr_t cbt_a = ((uintptr_t)o_ew + 15) & ~(uintptr_t)15;
  unsigned short* zbuf = (unsigned short*)zb_a;
  unsigned short* cbt  = (unsigned short*)cbt_a;
  float* cnormb = (float*)(cbt_a + 4194304);
  unsigned long long* partials = (unsigned long long*)o_zq;

  const size_t ws_need = 4 * (8192 * 2 + 16384 + 256);  // 132096 B
  const bool sorted = (ws_size >= ws_need);
  int* cnt      = (int*)d_ws;
  int* start    = cnt + 8192;
  int* rowlist  = start + 8192;
  float* loss_part = (float*)(rowlist + 16384);

  k_pre<<<3105, 256, 0, stream>>>(z, zbuf, cb, cbt, cnormb,
                                  sorted ? cnt : (int*)nullptr, loss_part);

  dim3 g(8, 256);
  k_argmin<<<g, 256, 0, stream>>>(zbuf, cbt, cnormb, partials);
  k_reduce<<<N_ROWS / 4, 256, 0, stream>>>(partials, z, cb, o_codes,
                                           sorted ? cnt : (int*)nullptr);

  if (sorted) {
    k_scanplace<<<1, 1024, 0, stream>>>(cnt, start, ema_cs, o_cs, o_codes,
                                        rowlist);
    k_dw2<<<KCODES, 256, 0, stream>>>(z, cb, start, cnt, rowlist, ema_w,
                                      o_cs, o_zq, o_ew, o_cb, loss_part);
    k_loss_final<<<1, 256, 0, stream>>>(loss_part, o_loss);
  } else {
    (void)hipMemsetAsync(o_loss, 0,
                         (size_t)(OUT_TOTAL - OFF_LOSS) * sizeof(float), stream);
    k_scatter<<<N_ROWS, 256, 0, stream>>>(z, cb, o_codes, o_zq, o_loss, o_cs,
                                          o_ew);
    k_ema_cs<<<KCODES / 256, 256, 0, stream>>>(ema_cs, o_cs);
    k_ema_w <<<KCODES * DIM / 256, 256, 0, stream>>>(ema_w, o_cs, o_ew, o_cb);
  }
}

// Round 17
// 156.240 us; speedup vs baseline: 1.0931x; 1.0931x over previous
//
#include <hip/hip_runtime.h>
#include <hip/hip_bf16.h>
#include <math.h>

#define N_ROWS 16384      // 8 * 2048
#define DIM    256
#define KCODES 8192

// Output layout (float offsets), reference return order
#define OFF_ZQ    0
#define OFF_CODES 4194304
#define OFF_LOSS  4210688
#define OFF_CB    4210689
#define OFF_CS    6307841
#define OFF_EW    6316033
#define OUT_TOTAL 8413185

typedef __attribute__((ext_vector_type(8))) short bf16x8;
typedef __attribute__((ext_vector_type(4))) float f32x4;
typedef __attribute__((ext_vector_type(16))) float f32x16;

__device__ __forceinline__ void gll16(const void* g, void* l) {
  __builtin_amdgcn_global_load_lds(
      (const __attribute__((address_space(1))) unsigned int*)g,
      (__attribute__((address_space(3))) unsigned int*)l, 16, 0, 0);
}

__device__ __forceinline__ unsigned short f2bf(float x) {
  __hip_bfloat16 h = __float2bfloat16(x);
  return *reinterpret_cast<unsigned short*>(&h);
}

__device__ __forceinline__ unsigned umin32(unsigned a, unsigned b) { return a < b ? a : b; }
__device__ __forceinline__ unsigned umax32(unsigned a, unsigned b) { return a > b ? a : b; }

// --- fused prep: z->bf16, cb->transposed bf16(-2c)+norms, zero cnt/loss ---
__global__ __launch_bounds__(256) void k_pre(
    const float* __restrict__ z, unsigned short* __restrict__ zbuf,
    const float* __restrict__ cb, unsigned short* __restrict__ cbt,
    float* __restrict__ cnormb, int* __restrict__ cnt,
    float* __restrict__ loss_part) {
  const int b = blockIdx.x;
  const int tid = threadIdx.x;
  if (b < 2048) {                      // z convert (8 elems/thread)
    int i = b * 256 + tid;
    const float4 a = ((const float4*)z)[i * 2];
    const float4 c = ((const float4*)z)[i * 2 + 1];
    union { unsigned short u[8]; uint4 v; } o;
    o.u[0] = f2bf(a.x); o.u[1] = f2bf(a.y); o.u[2] = f2bf(a.z); o.u[3] = f2bf(a.w);
    o.u[4] = f2bf(c.x); o.u[5] = f2bf(c.y); o.u[6] = f2bf(c.z); o.u[7] = f2bf(c.w);
    ((uint4*)zbuf)[i] = o.v;
  } else if (b < 3072) {               // cb transpose + biased norms
    const int code = (b - 2048) * 8 + (tid >> 5);
    const int dq = tid & 31;
    const float4 v0 = *(const float4*)(cb + (size_t)code * 256 + dq * 8);
    const float4 v1 = *(const float4*)(cb + (size_t)code * 256 + dq * 8 + 4);
    union { unsigned short u[8]; uint4 q; } o;
    o.u[0] = f2bf(-2.f * v0.x); o.u[1] = f2bf(-2.f * v0.y);
    o.u[2] = f2bf(-2.f * v0.z); o.u[3] = f2bf(-2.f * v0.w);
    o.u[4] = f2bf(-2.f * v1.x); o.u[5] = f2bf(-2.f * v1.y);
    o.u[6] = f2bf(-2.f * v1.z); o.u[7] = f2bf(-2.f * v1.w);
    *(uint4*)(cbt + ((size_t)dq * 8192 + code) * 8) = o.q;
    float s = v0.x * v0.x + v0.y * v0.y + v0.z * v0.z + v0.w * v0.w +
              v1.x * v1.x + v1.y * v1.y + v1.z * v1.z + v1.w * v1.w;
#pragma unroll
    for (int off = 16; off >= 1; off >>= 1) s += __shfl_down(s, off);
    if ((tid & 31) == 0) cnormb[code] = s + 1024.0f;   // bias baked in
  } else if (cnt) {                    // zero accumulators
    int zi = (b - 3072) * 256 + tid;
    if (zi < 8192) cnt[zi] = 0;
    else if (zi < 8448) loss_part[zi - 8192] = 0.0f;
  }
}

// ---------------- persistent-z MFMA argmin (32x32x16) --------------------
// EXACT R13 config (measured best: 69.3us, FETCH 20.7MB, MfmaUtil 42%):
// 2048-code blocks (two 1024-code halves), 128 rows, LDS 72KB, per-KSTEP
// barrier + counted vmcnt(2), branchless 3-op top-2 merge.
__global__ __launch_bounds__(256, 2) void k_argmin(
    const unsigned short* __restrict__ zb,   // [16384][256] bf16 row-major
    const unsigned short* __restrict__ cbt,  // [32 dq][8192 codes] bf16 of -2c
    const float* __restrict__ cnb,           // [8192] ||c||^2 + 1024
    unsigned long long* __restrict__ partials) {  // [16384 row][32 entry]
  __shared__ __align__(16) unsigned char lds[73728]; // 64K z/cb + 8K cnorm

  const int tid = threadIdx.x;
  const int lane = tid & 63;
  const int w = tid >> 6;
  const int wc = w & 1;
  const int wr = w >> 1;
  const int hi = lane >> 5;
  const int l31 = lane & 31;
  const int chunk = blockIdx.x;      // [0,4): 2048 codes per block
  const int r0 = blockIdx.y << 7;    // row tile

  // ---- prologue: stage z (swizzled) + cnorm (2048 codes, 8KB) ----
  {
    const char* zgb = (const char*)zb + (size_t)r0 * 512;
#pragma unroll
    for (int it = 0; it < 16; ++it) {
      int s = it * 256 + tid;
      int row = s >> 5;
      int dql = (tid & 31) ^ (row & 31);
      gll16(zgb + row * 512 + dql * 16, lds + s * 16);
    }
    gll16((const char*)cnb + (size_t)chunk * 8192 + tid * 16,
          lds + 65536 + tid * 16);
    gll16((const char*)cnb + (size_t)chunk * 8192 + 4096 + tid * 16,
          lds + 69632 + tid * 16);
  }
  asm volatile("s_waitcnt vmcnt(0)" ::: "memory");
  __builtin_amdgcn_s_barrier();
  __builtin_amdgcn_sched_barrier(0);

  // ---- z -> registers (swizzled reads, conflict-free) ----
  bf16x8 zr0[16], zr1[16];
  {
    const int xr = l31 * 16;
    const int rb0 = (wr * 64 + l31) * 512;
    const int rb1 = (wr * 64 + 32 + l31) * 512;
    const int hx = hi * 16;
#pragma unroll
    for (int ks = 0; ks < 16; ++ks) {
      zr0[ks] = *(const bf16x8*)(lds + rb0 + ((ks * 32 + hx) ^ xr));
      zr1[ks] = *(const bf16x8*)(lds + rb1 + ((ks * 32 + hx) ^ xr));
    }
  }
  asm volatile("s_waitcnt lgkmcnt(0)" ::: "memory");
  __builtin_amdgcn_s_barrier();
  __builtin_amdgcn_sched_barrier(0);

  // ---- cb staging setup; prologue stages g=0,1,2 of half0/ct0 ----
  unsigned char* lcb = lds + tid * 16;
  const char* cgc = (const char*)cbt +
      ((size_t)(tid >> 7) * 131072 + (size_t)chunk * 32768 + (tid & 127) * 16);
  gll16(cgc + 0 * 262144, lcb + 0 * 4096);
  gll16(cgc + 1 * 262144, lcb + 1 * 4096);
  gll16(cgc + 2 * 262144, lcb + 2 * 4096);

  const unsigned char* afp = lds + hi * 2048 + (wc * 64 + l31) * 16;
  const unsigned wchi4 = (unsigned)(wc * 64 + hi * 4);

  unsigned k1_00 = 0xFFFFFFFFu, k2_00 = 0xFFFFFFFFu;
  unsigned k1_01 = 0xFFFFFFFFu, k2_01 = 0xFFFFFFFFu;
  unsigned k1_10 = 0xFFFFFFFFu, k2_10 = 0xFFFFFFFFu;
  unsigned k1_11 = 0xFFFFFFFFu, k2_11 = 0xFFFFFFFFu;
  f32x16 acc00, acc01, acc10, acc11;

#define KSTEP(ks, TAIL)                                                        \
  {                                                                            \
    if ((TAIL) && (ks) == 14) asm volatile("s_waitcnt vmcnt(1)" ::: "memory"); \
    else if ((TAIL) && (ks) == 15) asm volatile("s_waitcnt vmcnt(0)" ::: "memory"); \
    else asm volatile("s_waitcnt vmcnt(2)" ::: "memory");                      \
    __builtin_amdgcn_s_barrier();                                              \
    __builtin_amdgcn_sched_barrier(0);                                         \
    if ((ks) < 13) {                                                           \
      gll16(cgc + ((ks) + 3) * 262144, lcb + (((ks) + 3) & 3) * 4096);         \
    } else if (!(TAIL)) {                                                      \
      gll16(cgc + 2048 + ((ks) - 13) * 262144, lcb + (((ks) + 3) & 3) * 4096); \
    }                                                                          \
    bf16x8 a0 = *(const bf16x8*)(afp + ((ks) & 3) * 4096);                     \
    bf16x8 a1 = *(const bf16x8*)(afp + ((ks) & 3) * 4096 + 512);               \
    acc00 = __builtin_amdgcn_mfma_f32_32x32x16_bf16(a0, zr0[ks], acc00, 0, 0, 0); \
    acc01 = __builtin_amdgcn_mfma_f32_32x32x16_bf16(a0, zr1[ks], acc01, 0, 0, 0); \
    acc10 = __builtin_amdgcn_mfma_f32_32x32x16_bf16(a1, zr0[ks], acc10, 0, 0, 0); \
    acc11 = __builtin_amdgcn_mfma_f32_32x32x16_bf16(a1, zr1[ks], acc11, 0, 0, 0); \
  }

// branchless top-2 merge: exact same result as the if-chain (keys unique)
#define MRG(K1V, K2V, KEY)                                                     \
  {                                                                            \
    unsigned t_ = umax32(K1V, (KEY));                                          \
    K2V = umin32(K2V, t_);                                                     \
    K1V = umin32(K1V, (KEY));                                                  \
  }

#define CTBODY(HALF, TAIL)                                                     \
  {                                                                            \
    const int cnoff = 65536 + (HALF) * 4096 + ct * 512 + wc * 256 + hi * 16;   \
    f32x4 cnA[4], cnB[4];                                                      \
    _Pragma("unroll") for (int g2 = 0; g2 < 4; ++g2) {                         \
      cnA[g2] = *(const f32x4*)(lds + cnoff + g2 * 32);                        \
      cnB[g2] = *(const f32x4*)(lds + cnoff + 128 + g2 * 32);                  \
    }                                                                          \
    _Pragma("unroll") for (int r = 0; r < 16; ++r) {                           \
      float vA = cnA[r >> 2][r & 3], vB = cnB[r >> 2][r & 3];                  \
      acc00[r] = vA; acc01[r] = vA; acc10[r] = vB; acc11[r] = vB;              \
    }                                                                          \
    KSTEP(0, TAIL)  KSTEP(1, TAIL)  KSTEP(2, TAIL)  KSTEP(3, TAIL)             \
    KSTEP(4, TAIL)  KSTEP(5, TAIL)  KSTEP(6, TAIL)  KSTEP(7, TAIL)             \
    KSTEP(8, TAIL)  KSTEP(9, TAIL)  KSTEP(10, TAIL) KSTEP(11, TAIL)            \
    KSTEP(12, TAIL) KSTEP(13, TAIL) KSTEP(14, TAIL) KSTEP(15, TAIL)            \
    const unsigned vb = (unsigned)(ct * 128) | wchi4;                          \
    _Pragma("unroll") for (int r = 0; r < 16; ++r) {                           \
      const unsigned base = (unsigned)(8 * (r >> 2) + (r & 3));                \
      unsigned key;                                                            \
      key = (__float_as_uint(acc00[r]) & 0xFFFFFC00u) | (vb | base);           \
      MRG(k1_00, k2_00, key)                                                   \
      key = (__float_as_uint(acc01[r]) & 0xFFFFFC00u) | (vb | base);           \
      MRG(k1_01, k2_01, key)                                                   \
      key = (__float_as_uint(acc10[r]) & 0xFFFFFC00u) | (vb | base | 32u);     \
      MRG(k1_10, k2_10, key)                                                   \
      key = (__float_as_uint(acc11[r]) & 0xFFFFFC00u) | (vb | base | 32u);     \
      MRG(k1_11, k2_11, key)                                                   \
    }                                                                          \
    cgc += 2048;                                                               \
  }

  // ---- half 0: codes [chunk*2048, +1024) ----
  for (int ct = 0; ct < 8; ++ct) CTBODY(0, false)
  unsigned s1_00 = k1_00, s2_00 = k2_00, s1_01 = k1_01, s2_01 = k2_01;
  unsigned s1_10 = k1_10, s2_10 = k2_10, s1_11 = k1_11, s2_11 = k2_11;
  k1_00 = k2_00 = k1_01 = k2_01 = 0xFFFFFFFFu;
  k1_10 = k2_10 = k1_11 = k2_11 = 0xFFFFFFFFu;

  // ---- half 1: codes [chunk*2048+1024, +1024) ----
  for (int ct = 0; ct < 7; ++ct) CTBODY(1, false)
  { int ct = 7; CTBODY(1, true) }
#undef CTBODY
#undef MRG
#undef KSTEP

  // ---- epilogue: merge lane <-> lane+32, store per-(zf,cf,half) top-2 ----
#define FIN(K1V, K2V, ZF, ENT)                                                 \
  {                                                                            \
    unsigned o1 = (unsigned)__shfl_xor((int)(K1V), 32);                        \
    unsigned o2 = (unsigned)__shfl_xor((int)(K2V), 32);                        \
    unsigned n1 = umin32((K1V), o1);                                           \
    unsigned n2 = umin32(umax32((K1V), o1), umin32((K2V), o2));                \
    if (lane < 32) {                                                           \
      int row = r0 + wr * 64 + (ZF) * 32 + l31;                                \
      partials[(size_t)row * 32 + (ENT)] =                                     \
          ((unsigned long long)n2 << 32) | n1;                                 \
    }                                                                          \
  }
  const int eb = chunk * 8 + wc * 2;
  FIN(s1_00, s2_00, 0, eb + 0) FIN(s1_10, s2_10, 0, eb + 1)
  FIN(s1_01, s2_01, 1, eb + 0) FIN(s1_11, s2_11, 1, eb + 1)
  FIN(k1_00, k2_00, 0, eb + 4) FIN(k1_10, k2_10, 0, eb + 5)
  FIN(k1_01, k2_01, 1, eb + 4) FIN(k1_11, k2_11, 1, eb + 5)
#undef FIN
}

// ---- merge partials (wave/row) + refine + histogram + fused zq/loss ----
__global__ __launch_bounds__(256) void k_reduce(
    const unsigned long long* __restrict__ partials, const float* __restrict__ z,
    const float* __restrict__ cb, float* __restrict__ out_codes,
    int* __restrict__ cnt, float* __restrict__ zq,
    float* __restrict__ loss_part) {
  const int row = blockIdx.x * 4 + (threadIdx.x >> 6);
  const int lane = threadIdx.x & 63;
  const int e = lane & 31;

  unsigned myK1 = 0xFFFFFFFFu, myK2 = 0xFFFFFFFFu;
  if (lane < 32) {
    unsigned long long v = partials[(size_t)row * 32 + e];
    myK1 = (unsigned)v; myK2 = (unsigned)(v >> 32);
  }
  unsigned K1 = myK1, K2 = myK2;
  int bc = e >> 2;   // 1024-code chunk of K1
#pragma unroll
  for (int m = 1; m <= 32; m <<= 1) {
    unsigned o1 = (unsigned)__shfl_xor((int)K1, m);
    unsigned o2 = (unsigned)__shfl_xor((int)K2, m);
    int ob = __shfl_xor(bc, m);
    unsigned nK2 = umin32(umax32(K1, o1), umin32(K2, o2));
    if (o1 < K1 || (o1 == K1 && ob < bc)) { K1 = o1; bc = ob; }
    K2 = nK2;
  }
  int chosen = bc * 1024 + (int)(K1 & 1023u);

  const float* zr = z + ((size_t)row << 8);
  float r1 = __uint_as_float(K1 & 0xFFFFFC00u);
  float r2 = __uint_as_float(K2 & 0xFFFFFC00u);
  if (r2 - r1 < 0.75f) {   // wave-uniform near-tie: exact fp64 re-eval
    const float win = r1 + 0.75f;
    double bestd = 1e300; int bestj = 0x7fffffff;
#pragma unroll
    for (int h = 0; h < 2; ++h) {
      unsigned k = h ? myK2 : myK1;
      float bv = __uint_as_float(k & 0xFFFFFC00u);
      if (lane < 32 && bv <= win) {
        int jv = (e >> 2) * 1024 + (int)(k & 1023u);
        const float* c = cb + ((size_t)jv << 8);
        double d = 0.0;
        for (int kk = 0; kk < DIM; ++kk) {
          double df = (double)zr[kk] - (double)c[kk];
          d += df * df;
        }
        if (d < bestd || (d == bestd && jv < bestj)) { bestd = d; bestj = jv; }
      }
    }
#pragma unroll
    for (int m = 1; m <= 32; m <<= 1) {
      double od = __shfl_xor(bestd, m);
      int oj = __shfl_xor(bestj, m);
      if (od < bestd || (od == bestd && oj < bestj)) { bestd = od; bestj = oj; }
    }
    chosen = bestj;
  }
  if (lane == 0) {
    out_codes[row] = (float)chosen;
    if (cnt) atomicAdd(&cnt[chosen], 1);
  }

  // fused straight-through output + commitment loss (sorted path only)
  if (zq) {
    const float* cq = cb + ((size_t)chosen << 8);
    float4 zv = ((const float4*)zr)[lane];
    float4 qv = ((const float4*)cq)[lane];
    ((float4*)(zq + ((size_t)row << 8)))[lane] = qv;
    float d0 = zv.x - qv.x, d1 = zv.y - qv.y;
    float d2 = zv.z - qv.z, d3 = zv.w - qv.w;
    float lacc = (d0 * d0 + d1 * d1) + (d2 * d2 + d3 * d3);
#pragma unroll
    for (int off = 32; off >= 1; off >>= 1) lacc += __shfl_down(lacc, off);
    __shared__ float wls[4];
    if (lane == 0) wls[threadIdx.x >> 6] = lacc;
    __syncthreads();
    if (threadIdx.x == 0) {
      float s = (wls[0] + wls[1]) + (wls[2] + wls[3]);
      atomicAdd(loss_part + (blockIdx.x & 255), s * (float)(0.1 / 4194304.0));
    }
  }
}

// ---- fused scan + place: 1 block, shuffle prefix + LDS cursors -----------
__global__ __launch_bounds__(1024) void k_scanplace(
    const int* __restrict__ cnt, int* __restrict__ start,
    const float* __restrict__ ema_cs, float* __restrict__ cs_out,
    const float* __restrict__ codesf, int* __restrict__ rowlist) {
  __shared__ int lcur[8192];
  __shared__ int wsum[16], wbase[16];
  const int t = threadIdx.x;
  const int lane = t & 63, wid = t >> 6;
  const int base = t * 8;
  int c[8], s = 0;
#pragma unroll
  for (int i = 0; i < 8; ++i) { c[i] = cnt[base + i]; s += c[i]; }
  int inc = s;
#pragma unroll
  for (int off = 1; off < 64; off <<= 1) {
    int v = __shfl_up(inc, off);
    if (lane >= off) inc += v;
  }
  if (lane == 63) wsum[wid] = inc;
  __syncthreads();
  if (t < 16) {
    int v = wsum[t];
    int winc = v;
#pragma unroll
    for (int off = 1; off < 16; off <<= 1) {
      int u = __shfl_up(winc, off);
      if (t >= off) winc += u;
    }
    wbase[t] = winc - v;
  }
  __syncthreads();
  int ex = wbase[wid] + (inc - s);
#pragma unroll
  for (int i = 0; i < 8; ++i) {
    start[base + i] = ex;
    lcur[base + i] = ex;
    cs_out[base + i] = 0.99f * ema_cs[base + i] + 0.01f * (float)c[i];
    ex += c[i];
  }
  __syncthreads();
#pragma unroll
  for (int rr = 0; rr < 16; ++rr) {
    int r = rr * 1024 + t;
    int cc = (int)codesf[r];
    int p = atomicAdd(&lcur[cc], 1);
    rowlist[p] = r;
  }
}

// per-code pass: dw sum + EMA + codebook divide (no zq/loss -- in k_reduce)
__global__ __launch_bounds__(256) void k_dw2(
    const float* __restrict__ z, const int* __restrict__ start,
    const int* __restrict__ cnt, const int* __restrict__ rowlist,
    const float* __restrict__ ema_w, const float* __restrict__ cs_new,
    float* __restrict__ ew, float* __restrict__ cb_out) {
  const int k = blockIdx.x;
  const int d = threadIdx.x;
  const int s = start[k], n = cnt[k];
  const size_t o = ((size_t)k << 8) + d;
  float a0 = 0.f, a1 = 0.f, a2 = 0.f, a3 = 0.f;
  int t = 0;
  for (; t + 4 <= n; t += 4) {
    size_t ro0 = ((size_t)rowlist[s + t] << 8) + d;
    size_t ro1 = ((size_t)rowlist[s + t + 1] << 8) + d;
    size_t ro2 = ((size_t)rowlist[s + t + 2] << 8) + d;
    size_t ro3 = ((size_t)rowlist[s + t + 3] << 8) + d;
    a0 += z[ro0]; a1 += z[ro1]; a2 += z[ro2]; a3 += z[ro3];
  }
  for (; t < n; ++t)
    a0 += z[((size_t)rowlist[s + t] << 8) + d];
  float a = (a0 + a1) + (a2 + a3);
  const float v = 0.99f * ema_w[o] + 0.01f * a;
  ew[o] = v;
  cb_out[o] = v / (cs_new[k] + 1e-5f);
}

__global__ __launch_bounds__(256) void k_loss_final(
    const float* __restrict__ part, float* __restrict__ loss) {
  float s = part[threadIdx.x];
#pragma unroll
  for (int off = 32; off >= 1; off >>= 1) s += __shfl_down(s, off);
  __shared__ float w[4];
  if ((threadIdx.x & 63) == 0) w[threadIdx.x >> 6] = s;
  __syncthreads();
  if (threadIdx.x == 0) loss[0] = (w[0] + w[1]) + (w[2] + w[3]);
}

// ---------------- fallback atomic path (ws too small) ---------------------
__global__ __launch_bounds__(256) void k_scatter(
    const float* __restrict__ z, const float* __restrict__ cb,
    const float* __restrict__ codesf, float* __restrict__ zq,
    float* __restrict__ loss, float* __restrict__ cs_acc,
    float* __restrict__ ew_acc) {
  const int row = blockIdx.x;
  const int d = threadIdx.x;
  const int c = (int)codesf[row];
  const float zv = z[((size_t)row << 8) + d];
  const float qv = cb[((size_t)c << 8) + d];
  zq[((size_t)row << 8) + d] = zv + (qv - zv);
  float diff = zv - qv;
  float sq = diff * diff;
#pragma unroll
  for (int off = 32; off >= 1; off >>= 1) sq += __shfl_down(sq, off);
  __shared__ float wpart[4];
  if ((d & 63) == 0) wpart[d >> 6] = sq;
  __syncthreads();
  if (d == 0) {
    float s = (wpart[0] + wpart[1]) + (wpart[2] + wpart[3]);
    atomicAdd(loss, s * (float)(0.1 / 4194304.0));
    atomicAdd(cs_acc + c, 1.0f);
  }
  atomicAdd(ew_acc + ((size_t)c << 8) + d, zv);
}

__global__ __launch_bounds__(256) void k_ema_cs(const float* __restrict__ ema_cs,
                                                float* __restrict__ cs_io) {
  const int k = blockIdx.x * 256 + threadIdx.x;
  const float cnt = cs_io[k];
  cs_io[k] = 0.99f * ema_cs[k] + 0.01f * cnt;
}

__global__ __launch_bounds__(256) void k_ema_w(const float* __restrict__ ema_w,
                                               const float* __restrict__ cs_new,
                                               float* __restrict__ ew_io,
                                               float* __restrict__ cb_out) {
  const int i = blockIdx.x * 256 + threadIdx.x;
  const float dw = ew_io[i];
  const float v = 0.99f * ema_w[i] + 0.01f * dw;
  ew_io[i] = v;
  cb_out[i] = v / (cs_new[i >> 8] + 1e-5f);
}

// ---------------- launch --------------------------------------------------
extern "C" void kernel_launch(void* const* d_in, const int* in_sizes, int n_in,
                              void* d_out, int out_size, void* d_ws, size_t ws_size,
                              hipStream_t stream) {
  const float* z      = (const float*)d_in[0];
  const float* cb     = (const float*)d_in[1];
  const float* ema_cs = (const float*)d_in[2];
  const float* ema_w  = (const float*)d_in[3];
  float* out = (float*)d_out;

  float* o_zq    = out + OFF_ZQ;
  float* o_codes = out + OFF_CODES;
  float* o_loss  = out + OFF_LOSS;
  float* o_cb    = out + OFF_CB;
  float* o_cs    = out + OFF_CS;
  float* o_ew    = out + OFF_EW;

  // scratch aliases (each overwritten later in pipeline order):
  //   z_bf16 (8.39MB)               -> o_cb region (k_dw2 cb_out overwrites)
  //   cbt (4.19MB) + partials (4MB) -> o_ew region (k_dw2 ew overwrites)
  //   cnorm (32KB)                  -> d_ws tail (sorted) / o_ew spill (fb)
  uintptr_t zb_a  = ((uintptr_t)o_cb + 15) & ~(uintptr_t)15;
  uintptr_t cbt_a = ((uintptr_t)o_ew + 15) & ~(uintptr_t)15;
  unsigned short* zbuf = (unsigned short*)zb_a;
  unsigned short* cbt  = (unsigned short*)cbt_a;

  const size_t ws_need = 4 * (8192 * 2 + 16384 + 256 + 8192);  // 164864 B
  const bool sorted = (ws_size >= ws_need);
  int* cnt      = (int*)d_ws;
  int* start    = cnt + 8192;
  int* rowlist  = start + 8192;
  float* loss_part = (float*)(rowlist + 16384);
  float* cnorm_ws  = loss_part + 256;

  float* cnorm;
  unsigned long long* partials;
  if (sorted) {
    cnorm    = cnorm_ws;
    partials = (unsigned long long*)(cbt_a + 4194304);  // behind cbt in o_ew
  } else {
    cnorm    = (float*)(cbt_a + 4194304);
    partials = (unsigned long long*)o_zq;               // k_scatter writes zq
  }

  k_pre<<<3105, 256, 0, stream>>>(z, zbuf, cb, cbt, cnorm,
                                  sorted ? cnt : (int*)nullptr, loss_part);

  dim3 g(4, 128);
  k_argmin<<<g, 256, 0, stream>>>(zbuf, cbt, cnorm, partials);
  k_reduce<<<N_ROWS / 4, 256, 0, stream>>>(
      partials, z, cb, o_codes, sorted ? cnt : (int*)nullptr,
      sorted ? o_zq : (float*)nullptr, loss_part);

  if (sorted) {
    k_scanplace<<<1, 1024, 0, stream>>>(cnt, start, ema_cs, o_cs, o_codes,
                                        rowlist);
    k_dw2<<<KCODES, 256, 0, stream>>>(z, start, cnt, rowlist, ema_w, o_cs,
                                      o_ew, o_cb);
    k_loss_final<<<1, 256, 0, stream>>>(loss_part, o_loss);
  } else {
    (void)hipMemsetAsync(o_loss, 0,
                         (size_t)(OUT_TOTAL - OFF_LOSS) * sizeof(float), stream);
    k_scatter<<<N_ROWS, 256, 0, stream>>>(z, cb, o_codes, o_zq, o_loss, o_cs,
                                          o_ew);
    k_ema_cs<<<KCODES / 256, 256, 0, stream>>>(ema_cs, o_cs);
    k_ema_w <<<KCODES * DIM / 256, 256, 0, stream>>>(ema_w, o_cs, o_ew, o_cb);
  }
}

// Round 18
// 148.392 us; speedup vs baseline: 1.1509x; 1.0529x over previous
//
#include <hip/hip_runtime.h>
#include <hip/hip_bf16.h>
#include <math.h>

#define N_ROWS 16384      // 8 * 2048
#define DIM    256
#define KCODES 8192

// Output layout (float offsets), reference return order
#define OFF_ZQ    0
#define OFF_CODES 4194304
#define OFF_LOSS  4210688
#define OFF_CB    4210689
#define OFF_CS    6307841
#define OFF_EW    6316033
#define OUT_TOTAL 8413185

typedef __attribute__((ext_vector_type(8))) short bf16x8;
typedef __attribute__((ext_vector_type(4))) float f32x4;
typedef __attribute__((ext_vector_type(16))) float f32x16;

__device__ __forceinline__ void gll16(const void* g, void* l) {
  __builtin_amdgcn_global_load_lds(
      (const __attribute__((address_space(1))) unsigned int*)g,
      (__attribute__((address_space(3))) unsigned int*)l, 16, 0, 0);
}

__device__ __forceinline__ unsigned short f2bf(float x) {
  __hip_bfloat16 h = __float2bfloat16(x);
  return *reinterpret_cast<unsigned short*>(&h);
}

__device__ __forceinline__ unsigned umin32(unsigned a, unsigned b) { return a < b ? a : b; }
__device__ __forceinline__ unsigned umax32(unsigned a, unsigned b) { return a > b ? a : b; }

// --- fused prep: z->bf16, cb->transposed bf16(-2c)+norms, zero cnt/loss ---
__global__ __launch_bounds__(256) void k_pre(
    const float* __restrict__ z, unsigned short* __restrict__ zbuf,
    const float* __restrict__ cb, unsigned short* __restrict__ cbt,
    float* __restrict__ cnormb, int* __restrict__ cnt,
    float* __restrict__ loss_part) {
  const int b = blockIdx.x;
  const int tid = threadIdx.x;
  if (b < 2048) {                      // z convert (8 elems/thread)
    int i = b * 256 + tid;
    const float4 a = ((const float4*)z)[i * 2];
    const float4 c = ((const float4*)z)[i * 2 + 1];
    union { unsigned short u[8]; uint4 v; } o;
    o.u[0] = f2bf(a.x); o.u[1] = f2bf(a.y); o.u[2] = f2bf(a.z); o.u[3] = f2bf(a.w);
    o.u[4] = f2bf(c.x); o.u[5] = f2bf(c.y); o.u[6] = f2bf(c.z); o.u[7] = f2bf(c.w);
    ((uint4*)zbuf)[i] = o.v;
  } else if (b < 3072) {               // cb transpose + biased norms
    const int code = (b - 2048) * 8 + (tid >> 5);
    const int dq = tid & 31;
    const float4 v0 = *(const float4*)(cb + (size_t)code * 256 + dq * 8);
    const float4 v1 = *(const float4*)(cb + (size_t)code * 256 + dq * 8 + 4);
    union { unsigned short u[8]; uint4 q; } o;
    o.u[0] = f2bf(-2.f * v0.x); o.u[1] = f2bf(-2.f * v0.y);
    o.u[2] = f2bf(-2.f * v0.z); o.u[3] = f2bf(-2.f * v0.w);
    o.u[4] = f2bf(-2.f * v1.x); o.u[5] = f2bf(-2.f * v1.y);
    o.u[6] = f2bf(-2.f * v1.z); o.u[7] = f2bf(-2.f * v1.w);
    *(uint4*)(cbt + ((size_t)dq * 8192 + code) * 8) = o.q;
    float s = v0.x * v0.x + v0.y * v0.y + v0.z * v0.z + v0.w * v0.w +
              v1.x * v1.x + v1.y * v1.y + v1.z * v1.z + v1.w * v1.w;
#pragma unroll
    for (int off = 16; off >= 1; off >>= 1) s += __shfl_down(s, off);
    if ((tid & 31) == 0) cnormb[code] = s + 1024.0f;   // bias baked in
  } else if (cnt) {                    // zero accumulators
    int zi = (b - 3072) * 256 + tid;
    if (zi < 8192) cnt[zi] = 0;
    else if (zi < 8448) loss_part[zi - 8192] = 0.0f;
  }
}

// ---------------- persistent-z MFMA argmin (32x32x16) --------------------
// R13/R17 base, pair-barrier delta: 8-slot cb ring (32KB in dead z region),
// ONE barrier per 2 KSTEPs, vmcnt(4) counted waits, prefetch depth 6.
// Invariant: issued - needed = 4 at every pair; tail drains 4->2->0.
__global__ __launch_bounds__(256, 2) void k_argmin(
    const unsigned short* __restrict__ zb,   // [16384][256] bf16 row-major
    const unsigned short* __restrict__ cbt,  // [32 dq][8192 codes] bf16 of -2c
    const float* __restrict__ cnb,           // [8192] ||c||^2 + 1024
    unsigned long long* __restrict__ partials) {  // [16384 row][32 entry]
  __shared__ __align__(16) unsigned char lds[73728]; // 64K z/cb + 8K cnorm

  const int tid = threadIdx.x;
  const int lane = tid & 63;
  const int w = tid >> 6;
  const int wc = w & 1;
  const int wr = w >> 1;
  const int hi = lane >> 5;
  const int l31 = lane & 31;
  const int chunk = blockIdx.x;      // [0,4): 2048 codes per block
  const int r0 = blockIdx.y << 7;    // row tile

  // ---- prologue: stage z (swizzled) + cnorm (2048 codes, 8KB) ----
  {
    const char* zgb = (const char*)zb + (size_t)r0 * 512;
#pragma unroll
    for (int it = 0; it < 16; ++it) {
      int s = it * 256 + tid;
      int row = s >> 5;
      int dql = (tid & 31) ^ (row & 31);
      gll16(zgb + row * 512 + dql * 16, lds + s * 16);
    }
    gll16((const char*)cnb + (size_t)chunk * 8192 + tid * 16,
          lds + 65536 + tid * 16);
    gll16((const char*)cnb + (size_t)chunk * 8192 + 4096 + tid * 16,
          lds + 69632 + tid * 16);
  }
  asm volatile("s_waitcnt vmcnt(0)" ::: "memory");
  __builtin_amdgcn_s_barrier();
  __builtin_amdgcn_sched_barrier(0);

  // ---- z -> registers (swizzled reads, conflict-free) ----
  bf16x8 zr0[16], zr1[16];
  {
    const int xr = l31 * 16;
    const int rb0 = (wr * 64 + l31) * 512;
    const int rb1 = (wr * 64 + 32 + l31) * 512;
    const int hx = hi * 16;
#pragma unroll
    for (int ks = 0; ks < 16; ++ks) {
      zr0[ks] = *(const bf16x8*)(lds + rb0 + ((ks * 32 + hx) ^ xr));
      zr1[ks] = *(const bf16x8*)(lds + rb1 + ((ks * 32 + hx) ^ xr));
    }
  }
  asm volatile("s_waitcnt lgkmcnt(0)" ::: "memory");
  __builtin_amdgcn_s_barrier();
  __builtin_amdgcn_sched_barrier(0);

  // ---- cb staging: 8-slot ring, prologue stages steps 0..5 ----
  unsigned char* lcb = lds + tid * 16;
  const char* cgc = (const char*)cbt +
      ((size_t)(tid >> 7) * 131072 + (size_t)chunk * 32768 + (tid & 127) * 16);
#pragma unroll
  for (int s = 0; s < 6; ++s)
    gll16(cgc + s * 262144, lcb + s * 4096);

  const unsigned char* afp = lds + hi * 2048 + (wc * 64 + l31) * 16;
  const unsigned wchi4 = (unsigned)(wc * 64 + hi * 4);

  unsigned k1_00 = 0xFFFFFFFFu, k2_00 = 0xFFFFFFFFu;
  unsigned k1_01 = 0xFFFFFFFFu, k2_01 = 0xFFFFFFFFu;
  unsigned k1_10 = 0xFFFFFFFFu, k2_10 = 0xFFFFFFFFu;
  unsigned k1_11 = 0xFFFFFFFFu, k2_11 = 0xFFFFFFFFu;
  f32x16 acc00, acc01, acc10, acc11;

// one pair of KSTEPs (local steps 2pp, 2pp+1); TAIL = global last CT
#define PAIR(pp, TAIL)                                                         \
  {                                                                            \
    if ((TAIL) && (pp) == 6) asm volatile("s_waitcnt vmcnt(2)" ::: "memory");  \
    else if ((TAIL) && (pp) == 7) asm volatile("s_waitcnt vmcnt(0)" ::: "memory"); \
    else asm volatile("s_waitcnt vmcnt(4)" ::: "memory");                      \
    __builtin_amdgcn_s_barrier();                                              \
    __builtin_amdgcn_sched_barrier(0);                                         \
    if (!(TAIL) || (pp) < 5) {  /* prefetch local steps 2pp+6, 2pp+7 */        \
      const int s0_ = 2 * (pp) + 6, s1_ = 2 * (pp) + 7;                        \
      gll16(cgc + ((s0_ < 16) ? s0_ * 262144 : 2048 + (s0_ - 16) * 262144),    \
            lcb + (s0_ & 7) * 4096);                                           \
      gll16(cgc + ((s1_ < 16) ? s1_ * 262144 : 2048 + (s1_ - 16) * 262144),    \
            lcb + (s1_ & 7) * 4096);                                           \
    }                                                                          \
    {                                                                          \
      bf16x8 a0 = *(const bf16x8*)(afp + ((2 * (pp)) & 7) * 4096);             \
      bf16x8 b0 = *(const bf16x8*)(afp + ((2 * (pp)) & 7) * 4096 + 512);       \
      acc00 = __builtin_amdgcn_mfma_f32_32x32x16_bf16(a0, zr0[2 * (pp)], acc00, 0, 0, 0); \
      acc01 = __builtin_amdgcn_mfma_f32_32x32x16_bf16(a0, zr1[2 * (pp)], acc01, 0, 0, 0); \
      acc10 = __builtin_amdgcn_mfma_f32_32x32x16_bf16(b0, zr0[2 * (pp)], acc10, 0, 0, 0); \
      acc11 = __builtin_amdgcn_mfma_f32_32x32x16_bf16(b0, zr1[2 * (pp)], acc11, 0, 0, 0); \
      bf16x8 a1 = *(const bf16x8*)(afp + ((2 * (pp) + 1) & 7) * 4096);         \
      bf16x8 b1 = *(const bf16x8*)(afp + ((2 * (pp) + 1) & 7) * 4096 + 512);   \
      acc00 = __builtin_amdgcn_mfma_f32_32x32x16_bf16(a1, zr0[2 * (pp) + 1], acc00, 0, 0, 0); \
      acc01 = __builtin_amdgcn_mfma_f32_32x32x16_bf16(a1, zr1[2 * (pp) + 1], acc01, 0, 0, 0); \
      acc10 = __builtin_amdgcn_mfma_f32_32x32x16_bf16(b1, zr0[2 * (pp) + 1], acc10, 0, 0, 0); \
      acc11 = __builtin_amdgcn_mfma_f32_32x32x16_bf16(b1, zr1[2 * (pp) + 1], acc11, 0, 0, 0); \
    }                                                                          \
  }

// branchless top-2 merge: exact same result as the if-chain (keys unique)
#define MRG(K1V, K2V, KEY)                                                     \
  {                                                                            \
    unsigned t_ = umax32(K1V, (KEY));                                          \
    K2V = umin32(K2V, t_);                                                     \
    K1V = umin32(K1V, (KEY));                                                  \
  }

#define CTBODY(HALF, TAIL)                                                     \
  {                                                                            \
    const int cnoff = 65536 + (HALF) * 4096 + ct * 512 + wc * 256 + hi * 16;   \
    f32x4 cnA[4], cnB[4];                                                      \
    _Pragma("unroll") for (int g2 = 0; g2 < 4; ++g2) {                         \
      cnA[g2] = *(const f32x4*)(lds + cnoff + g2 * 32);                        \
      cnB[g2] = *(const f32x4*)(lds + cnoff + 128 + g2 * 32);                  \
    }                                                                          \
    _Pragma("unroll") for (int r = 0; r < 16; ++r) {                           \
      float vA = cnA[r >> 2][r & 3], vB = cnB[r >> 2][r & 3];                  \
      acc00[r] = vA; acc01[r] = vA; acc10[r] = vB; acc11[r] = vB;              \
    }                                                                          \
    PAIR(0, TAIL) PAIR(1, TAIL) PAIR(2, TAIL) PAIR(3, TAIL)                    \
    PAIR(4, TAIL) PAIR(5, TAIL) PAIR(6, TAIL) PAIR(7, TAIL)                    \
    const unsigned vb = (unsigned)(ct * 128) | wchi4;                          \
    _Pragma("unroll") for (int r = 0; r < 16; ++r) {                           \
      const unsigned base = (unsigned)(8 * (r >> 2) + (r & 3));                \
      unsigned key;                                                            \
      key = (__float_as_uint(acc00[r]) & 0xFFFFFC00u) | (vb | base);           \
      MRG(k1_00, k2_00, key)                                                   \
      key = (__float_as_uint(acc01[r]) & 0xFFFFFC00u) | (vb | base);           \
      MRG(k1_01, k2_01, key)                                                   \
      key = (__float_as_uint(acc10[r]) & 0xFFFFFC00u) | (vb | base | 32u);     \
      MRG(k1_10, k2_10, key)                                                   \
      key = (__float_as_uint(acc11[r]) & 0xFFFFFC00u) | (vb | base | 32u);     \
      MRG(k1_11, k2_11, key)                                                   \
    }                                                                          \
    cgc += 2048;                                                               \
  }

  // ---- half 0: codes [chunk*2048, +1024) ----
  for (int ct = 0; ct < 8; ++ct) CTBODY(0, false)
  unsigned s1_00 = k1_00, s2_00 = k2_00, s1_01 = k1_01, s2_01 = k2_01;
  unsigned s1_10 = k1_10, s2_10 = k2_10, s1_11 = k1_11, s2_11 = k2_11;
  k1_00 = k2_00 = k1_01 = k2_01 = 0xFFFFFFFFu;
  k1_10 = k2_10 = k1_11 = k2_11 = 0xFFFFFFFFu;

  // ---- half 1: codes [chunk*2048+1024, +1024) ----
  for (int ct = 0; ct < 7; ++ct) CTBODY(1, false)
  { int ct = 7; CTBODY(1, true) }
#undef CTBODY
#undef MRG
#undef PAIR

  // ---- epilogue: merge lane <-> lane+32, store per-(zf,cf,half) top-2 ----
#define FIN(K1V, K2V, ZF, ENT)                                                 \
  {                                                                            \
    unsigned o1 = (unsigned)__shfl_xor((int)(K1V), 32);                        \
    unsigned o2 = (unsigned)__shfl_xor((int)(K2V), 32);                        \
    unsigned n1 = umin32((K1V), o1);                                           \
    unsigned n2 = umin32(umax32((K1V), o1), umin32((K2V), o2));                \
    if (lane < 32) {                                                           \
      int row = r0 + wr * 64 + (ZF) * 32 + l31;                                \
      partials[(size_t)row * 32 + (ENT)] =                                     \
          ((unsigned long long)n2 << 32) | n1;                                 \
    }                                                                          \
  }
  const int eb = chunk * 8 + wc * 2;
  FIN(s1_00, s2_00, 0, eb + 0) FIN(s1_10, s2_10, 0, eb + 1)
  FIN(s1_01, s2_01, 1, eb + 0) FIN(s1_11, s2_11, 1, eb + 1)
  FIN(k1_00, k2_00, 0, eb + 4) FIN(k1_10, k2_10, 0, eb + 5)
  FIN(k1_01, k2_01, 1, eb + 4) FIN(k1_11, k2_11, 1, eb + 5)
#undef FIN
}

// ---- merge partials (wave/row) + refine + histogram + fused zq/loss ----
__global__ __launch_bounds__(256) void k_reduce(
    const unsigned long long* __restrict__ partials, const float* __restrict__ z,
    const float* __restrict__ cb, float* __restrict__ out_codes,
    int* __restrict__ cnt, float* __restrict__ zq,
    float* __restrict__ loss_part) {
  const int row = blockIdx.x * 4 + (threadIdx.x >> 6);
  const int lane = threadIdx.x & 63;
  const int e = lane & 31;

  unsigned myK1 = 0xFFFFFFFFu, myK2 = 0xFFFFFFFFu;
  if (lane < 32) {
    unsigned long long v = partials[(size_t)row * 32 + e];
    myK1 = (unsigned)v; myK2 = (unsigned)(v >> 32);
  }
  unsigned K1 = myK1, K2 = myK2;
  int bc = e >> 2;   // 1024-code chunk of K1
#pragma unroll
  for (int m = 1; m <= 32; m <<= 1) {
    unsigned o1 = (unsigned)__shfl_xor((int)K1, m);
    unsigned o2 = (unsigned)__shfl_xor((int)K2, m);
    int ob = __shfl_xor(bc, m);
    unsigned nK2 = umin32(umax32(K1, o1), umin32(K2, o2));
    if (o1 < K1 || (o1 == K1 && ob < bc)) { K1 = o1; bc = ob; }
    K2 = nK2;
  }
  int chosen = bc * 1024 + (int)(K1 & 1023u);

  const float* zr = z + ((size_t)row << 8);
  float r1 = __uint_as_float(K1 & 0xFFFFFC00u);
  float r2 = __uint_as_float(K2 & 0xFFFFFC00u);
  if (r2 - r1 < 0.75f) {   // wave-uniform near-tie: exact fp64 re-eval
    const float win = r1 + 0.75f;
    double bestd = 1e300; int bestj = 0x7fffffff;
#pragma unroll
    for (int h = 0; h < 2; ++h) {
      unsigned k = h ? myK2 : myK1;
      float bv = __uint_as_float(k & 0xFFFFFC00u);
      if (lane < 32 && bv <= win) {
        int jv = (e >> 2) * 1024 + (int)(k & 1023u);
        const float* c = cb + ((size_t)jv << 8);
        double d = 0.0;
        for (int kk = 0; kk < DIM; ++kk) {
          double df = (double)zr[kk] - (double)c[kk];
          d += df * df;
        }
        if (d < bestd || (d == bestd && jv < bestj)) { bestd = d; bestj = jv; }
      }
    }
#pragma unroll
    for (int m = 1; m <= 32; m <<= 1) {
      double od = __shfl_xor(bestd, m);
      int oj = __shfl_xor(bestj, m);
      if (od < bestd || (od == bestd && oj < bestj)) { bestd = od; bestj = oj; }
    }
    chosen = bestj;
  }
  if (lane == 0) {
    out_codes[row] = (float)chosen;
    if (cnt) atomicAdd(&cnt[chosen], 1);
  }

  // fused straight-through output + commitment loss (sorted path only)
  if (zq) {
    const float* cq = cb + ((size_t)chosen << 8);
    float4 zv = ((const float4*)zr)[lane];
    float4 qv = ((const float4*)cq)[lane];
    ((float4*)(zq + ((size_t)row << 8)))[lane] = qv;
    float d0 = zv.x - qv.x, d1 = zv.y - qv.y;
    float d2 = zv.z - qv.z, d3 = zv.w - qv.w;
    float lacc = (d0 * d0 + d1 * d1) + (d2 * d2 + d3 * d3);
#pragma unroll
    for (int off = 32; off >= 1; off >>= 1) lacc += __shfl_down(lacc, off);
    __shared__ float wls[4];
    if (lane == 0) wls[threadIdx.x >> 6] = lacc;
    __syncthreads();
    if (threadIdx.x == 0) {
      float s = (wls[0] + wls[1]) + (wls[2] + wls[3]);
      atomicAdd(loss_part + (blockIdx.x & 255), s * (float)(0.1 / 4194304.0));
    }
  }
}

// ---- scan: 1 block, shuffle prefix; writes start, cursor, cs_out ---------
__global__ __launch_bounds__(1024) void k_scan(
    const int* __restrict__ cnt, int* __restrict__ start,
    int* __restrict__ cursor, const float* __restrict__ ema_cs,
    float* __restrict__ cs_out) {
  __shared__ int wsum[16], wbase[16];
  const int t = threadIdx.x;
  const int lane = t & 63, wid = t >> 6;
  const int base = t * 8;
  int c[8], s = 0;
#pragma unroll
  for (int i = 0; i < 8; ++i) { c[i] = cnt[base + i]; s += c[i]; }
  int inc = s;
#pragma unroll
  for (int off = 1; off < 64; off <<= 1) {
    int v = __shfl_up(inc, off);
    if (lane >= off) inc += v;
  }
  if (lane == 63) wsum[wid] = inc;
  __syncthreads();
  if (t < 16) {
    int v = wsum[t];
    int winc = v;
#pragma unroll
    for (int off = 1; off < 16; off <<= 1) {
      int u = __shfl_up(winc, off);
      if (t >= off) winc += u;
    }
    wbase[t] = winc - v;
  }
  __syncthreads();
  int ex = wbase[wid] + (inc - s);
#pragma unroll
  for (int i = 0; i < 8; ++i) {
    start[base + i] = ex;
    cursor[base + i] = ex;
    cs_out[base + i] = 0.99f * ema_cs[base + i] + 0.01f * (float)c[i];
    ex += c[i];
  }
}

__global__ __launch_bounds__(256) void k_place(const float* __restrict__ codesf,
                                               int* __restrict__ cursor,
                                               int* __restrict__ rowlist) {
  int i = blockIdx.x * 256 + threadIdx.x;
  int c = (int)codesf[i];
  int p = atomicAdd(&cursor[c], 1);
  rowlist[p] = i;
}

// per-code pass: dw sum + EMA + codebook divide (no zq/loss -- in k_reduce)
__global__ __launch_bounds__(256) void k_dw2(
    const float* __restrict__ z, const int* __restrict__ start,
    const int* __restrict__ cnt, const int* __restrict__ rowlist,
    const float* __restrict__ ema_w, const float* __restrict__ cs_new,
    float* __restrict__ ew, float* __restrict__ cb_out) {
  const int k = blockIdx.x;
  const int d = threadIdx.x;
  const int s = start[k], n = cnt[k];
  const size_t o = ((size_t)k << 8) + d;
  float a0 = 0.f, a1 = 0.f, a2 = 0.f, a3 = 0.f;
  int t = 0;
  for (; t + 4 <= n; t += 4) {
    size_t ro0 = ((size_t)rowlist[s + t] << 8) + d;
    size_t ro1 = ((size_t)rowlist[s + t + 1] << 8) + d;
    size_t ro2 = ((size_t)rowlist[s + t + 2] << 8) + d;
    size_t ro3 = ((size_t)rowlist[s + t + 3] << 8) + d;
    a0 += z[ro0]; a1 += z[ro1]; a2 += z[ro2]; a3 += z[ro3];
  }
  for (; t < n; ++t)
    a0 += z[((size_t)rowlist[s + t] << 8) + d];
  float a = (a0 + a1) + (a2 + a3);
  const float v = 0.99f * ema_w[o] + 0.01f * a;
  ew[o] = v;
  cb_out[o] = v / (cs_new[k] + 1e-5f);
}

__global__ __launch_bounds__(256) void k_loss_final(
    const float* __restrict__ part, float* __restrict__ loss) {
  float s = part[threadIdx.x];
#pragma unroll
  for (int off = 32; off >= 1; off >>= 1) s += __shfl_down(s, off);
  __shared__ float w[4];
  if ((threadIdx.x & 63) == 0) w[threadIdx.x >> 6] = s;
  __syncthreads();
  if (threadIdx.x == 0) loss[0] = (w[0] + w[1]) + (w[2] + w[3]);
}

// ---------------- fallback atomic path (ws too small) ---------------------
__global__ __launch_bounds__(256) void k_scatter(
    const float* __restrict__ z, const float* __restrict__ cb,
    const float* __restrict__ codesf, float* __restrict__ zq,
    float* __restrict__ loss, float* __restrict__ cs_acc,
    float* __restrict__ ew_acc) {
  const int row = blockIdx.x;
  const int d = threadIdx.x;
  const int c = (int)codesf[row];
  const float zv = z[((size_t)row << 8) + d];
  const float qv = cb[((size_t)c << 8) + d];
  zq[((size_t)row << 8) + d] = zv + (qv - zv);
  float diff = zv - qv;
  float sq = diff * diff;
#pragma unroll
  for (int off = 32; off >= 1; off >>= 1) sq += __shfl_down(sq, off);
  __shared__ float wpart[4];
  if ((d & 63) == 0) wpart[d >> 6] = sq;
  __syncthreads();
  if (d == 0) {
    float s = (wpart[0] + wpart[1]) + (wpart[2] + wpart[3]);
    atomicAdd(loss, s * (float)(0.1 / 4194304.0));
    atomicAdd(cs_acc + c, 1.0f);
  }
  atomicAdd(ew_acc + ((size_t)c << 8) + d, zv);
}

__global__ __launch_bounds__(256) void k_ema_cs(const float* __restrict__ ema_cs,
                                                float* __restrict__ cs_io) {
  const int k = blockIdx.x * 256 + threadIdx.x;
  const float cnt = cs_io[k];
  cs_io[k] = 0.99f * ema_cs[k] + 0.01f * cnt;
}

__global__ __launch_bounds__(256) void k_ema_w(const float* __restrict__ ema_w,
                                               const float* __restrict__ cs_new,
                                               float* __restrict__ ew_io,
                                               float* __restrict__ cb_out) {
  const int i = blockIdx.x * 256 + threadIdx.x;
  const float dw = ew_io[i];
  const float v = 0.99f * ema_w[i] + 0.01f * dw;
  ew_io[i] = v;
  cb_out[i] = v / (cs_new[i >> 8] + 1e-5f);
}

// ---------------- launch --------------------------------------------------
extern "C" void kernel_launch(void* const* d_in, const int* in_sizes, int n_in,
                              void* d_out, int out_size, void* d_ws, size_t ws_size,
                              hipStream_t stream) {
  const float* z      = (const float*)d_in[0];
  const float* cb     = (const float*)d_in[1];
  const float* ema_cs = (const float*)d_in[2];
  const float* ema_w  = (const float*)d_in[3];
  float* out = (float*)d_out;

  float* o_zq    = out + OFF_ZQ;
  float* o_codes = out + OFF_CODES;
  float* o_loss  = out + OFF_LOSS;
  float* o_cb    = out + OFF_CB;
  float* o_cs    = out + OFF_CS;
  float* o_ew    = out + OFF_EW;

  // scratch aliases (each overwritten later in pipeline order):
  //   z_bf16 (8.39MB)               -> o_cb region (k_dw2 cb_out overwrites)
  //   cbt (4.19MB) + partials (4MB) -> o_ew region (k_dw2 ew overwrites)
  //   cnorm (32KB)                  -> d_ws tail; reused as cursor after argmin
  uintptr_t zb_a  = ((uintptr_t)o_cb + 15) & ~(uintptr_t)15;
  uintptr_t cbt_a = ((uintptr_t)o_ew + 15) & ~(uintptr_t)15;
  unsigned short* zbuf = (unsigned short*)zb_a;
  unsigned short* cbt  = (unsigned short*)cbt_a;

  const size_t ws_need = 4 * (8192 * 2 + 16384 + 256 + 8192);  // 164864 B
  const bool sorted = (ws_size >= ws_need);
  int* cnt      = (int*)d_ws;
  int* start    = cnt + 8192;
  int* rowlist  = start + 8192;
  float* loss_part = (float*)(rowlist + 16384);
  float* cnorm_ws  = loss_part + 256;

  float* cnorm;
  unsigned long long* partials;
  if (sorted) {
    cnorm    = cnorm_ws;
    partials = (unsigned long long*)(cbt_a + 4194304);  // behind cbt in o_ew
  } else {
    cnorm    = (float*)(cbt_a + 4194304);
    partials = (unsigned long long*)o_zq;               // k_scatter writes zq
  }

  k_pre<<<3105, 256, 0, stream>>>(z, zbuf, cb, cbt, cnorm,
                                  sorted ? cnt : (int*)nullptr, loss_part);

  dim3 g(4, 128);
  k_argmin<<<g, 256, 0, stream>>>(zbuf, cbt, cnorm, partials);
  k_reduce<<<N_ROWS / 4, 256, 0, stream>>>(
      partials, z, cb, o_codes, sorted ? cnt : (int*)nullptr,
      sorted ? o_zq : (float*)nullptr, loss_part);

  if (sorted) {
    int* cursor = (int*)cnorm_ws;   // cnorm dead after k_argmin
    k_scan <<<1, 1024, 0, stream>>>(cnt, start, cursor, ema_cs, o_cs);
    k_place<<<64, 256, 0, stream>>>(o_codes, cursor, rowlist);
    k_dw2<<<KCODES, 256, 0, stream>>>(z, start, cnt, rowlist, ema_w, o_cs,
                                      o_ew, o_cb);
    k_loss_final<<<1, 256, 0, stream>>>(loss_part, o_loss);
  } else {
    (void)hipMemsetAsync(o_loss, 0,
                         (size_t)(OUT_TOTAL - OFF_LOSS) * sizeof(float), stream);
    k_scatter<<<N_ROWS, 256, 0, stream>>>(z, cb, o_codes, o_zq, o_loss, o_cs,
                                          o_ew);
    k_ema_cs<<<KCODES / 256, 256, 0, stream>>>(ema_cs, o_cs);
    k_ema_w <<<KCODES * DIM / 256, 256, 0, stream>>>(ema_w, o_cs, o_ew, o_cb);
  }
}

// Round 19
// 144.679 us; speedup vs baseline: 1.1805x; 1.0257x over previous
//
#include <hip/hip_runtime.h>
#include <hip/hip_bf16.h>
#include <math.h>

#define N_ROWS 16384      // 8 * 2048
#define DIM    256
#define KCODES 8192

// Output layout (float offsets), reference return order
#define OFF_ZQ    0
#define OFF_CODES 4194304
#define OFF_LOSS  4210688
#define OFF_CB    4210689
#define OFF_CS    6307841
#define OFF_EW    6316033
#define OUT_TOTAL 8413185

typedef __attribute__((ext_vector_type(8))) short bf16x8;
typedef __attribute__((ext_vector_type(4))) float f32x4;
typedef __attribute__((ext_vector_type(16))) float f32x16;

__device__ __forceinline__ void gll16(const void* g, void* l) {
  __builtin_amdgcn_global_load_lds(
      (const __attribute__((address_space(1))) unsigned int*)g,
      (__attribute__((address_space(3))) unsigned int*)l, 16, 0, 0);
}

__device__ __forceinline__ unsigned short f2bf(float x) {
  __hip_bfloat16 h = __float2bfloat16(x);
  return *reinterpret_cast<unsigned short*>(&h);
}

__device__ __forceinline__ unsigned umin32(unsigned a, unsigned b) { return a < b ? a : b; }
__device__ __forceinline__ unsigned umax32(unsigned a, unsigned b) { return a > b ? a : b; }

// --- fused prep: z->bf16, cb->transposed bf16(-2c)+norms, zero cnt/loss ---
__global__ __launch_bounds__(256) void k_pre(
    const float* __restrict__ z, unsigned short* __restrict__ zbuf,
    const float* __restrict__ cb, unsigned short* __restrict__ cbt,
    float* __restrict__ cnormb, int* __restrict__ cnt,
    float* __restrict__ loss_part) {
  const int b = blockIdx.x;
  const int tid = threadIdx.x;
  if (b < 2048) {                      // z convert (8 elems/thread)
    int i = b * 256 + tid;
    const float4 a = ((const float4*)z)[i * 2];
    const float4 c = ((const float4*)z)[i * 2 + 1];
    union { unsigned short u[8]; uint4 v; } o;
    o.u[0] = f2bf(a.x); o.u[1] = f2bf(a.y); o.u[2] = f2bf(a.z); o.u[3] = f2bf(a.w);
    o.u[4] = f2bf(c.x); o.u[5] = f2bf(c.y); o.u[6] = f2bf(c.z); o.u[7] = f2bf(c.w);
    ((uint4*)zbuf)[i] = o.v;
  } else if (b < 3072) {               // cb transpose + biased norms
    const int code = (b - 2048) * 8 + (tid >> 5);
    const int dq = tid & 31;
    const float4 v0 = *(const float4*)(cb + (size_t)code * 256 + dq * 8);
    const float4 v1 = *(const float4*)(cb + (size_t)code * 256 + dq * 8 + 4);
    union { unsigned short u[8]; uint4 q; } o;
    o.u[0] = f2bf(-2.f * v0.x); o.u[1] = f2bf(-2.f * v0.y);
    o.u[2] = f2bf(-2.f * v0.z); o.u[3] = f2bf(-2.f * v0.w);
    o.u[4] = f2bf(-2.f * v1.x); o.u[5] = f2bf(-2.f * v1.y);
    o.u[6] = f2bf(-2.f * v1.z); o.u[7] = f2bf(-2.f * v1.w);
    *(uint4*)(cbt + ((size_t)dq * 8192 + code) * 8) = o.q;
    float s = v0.x * v0.x + v0.y * v0.y + v0.z * v0.z + v0.w * v0.w +
              v1.x * v1.x + v1.y * v1.y + v1.z * v1.z + v1.w * v1.w;
#pragma unroll
    for (int off = 16; off >= 1; off >>= 1) s += __shfl_down(s, off);
    if ((tid & 31) == 0) cnormb[code] = s + 1024.0f;   // bias baked in
  } else if (cnt) {                    // zero accumulators
    int zi = (b - 3072) * 256 + tid;
    if (zi < 8192) cnt[zi] = 0;
    else if (zi < 8448) loss_part[zi - 8192] = 0.0f;
  }
}

// ---------------- persistent-z MFMA argmin (32x32x16) --------------------
// EXACT R13/R17 config (measured best: 69.7us, FETCH 20.7MB, MfmaUtil 42%):
// 2048-code blocks (two 1024-code halves), 128 rows, LDS 72KB, per-KSTEP
// barrier + counted vmcnt(2), branchless 3-op top-2 merge.
__global__ __launch_bounds__(256, 2) void k_argmin(
    const unsigned short* __restrict__ zb,   // [16384][256] bf16 row-major
    const unsigned short* __restrict__ cbt,  // [32 dq][8192 codes] bf16 of -2c
    const float* __restrict__ cnb,           // [8192] ||c||^2 + 1024
    unsigned long long* __restrict__ partials) {  // [16384 row][32 entry]
  __shared__ __align__(16) unsigned char lds[73728]; // 64K z/cb + 8K cnorm

  const int tid = threadIdx.x;
  const int lane = tid & 63;
  const int w = tid >> 6;
  const int wc = w & 1;
  const int wr = w >> 1;
  const int hi = lane >> 5;
  const int l31 = lane & 31;
  const int chunk = blockIdx.x;      // [0,4): 2048 codes per block
  const int r0 = blockIdx.y << 7;    // row tile

  // ---- prologue: stage z (swizzled) + cnorm (2048 codes, 8KB) ----
  {
    const char* zgb = (const char*)zb + (size_t)r0 * 512;
#pragma unroll
    for (int it = 0; it < 16; ++it) {
      int s = it * 256 + tid;
      int row = s >> 5;
      int dql = (tid & 31) ^ (row & 31);
      gll16(zgb + row * 512 + dql * 16, lds + s * 16);
    }
    gll16((const char*)cnb + (size_t)chunk * 8192 + tid * 16,
          lds + 65536 + tid * 16);
    gll16((const char*)cnb + (size_t)chunk * 8192 + 4096 + tid * 16,
          lds + 69632 + tid * 16);
  }
  asm volatile("s_waitcnt vmcnt(0)" ::: "memory");
  __builtin_amdgcn_s_barrier();
  __builtin_amdgcn_sched_barrier(0);

  // ---- z -> registers (swizzled reads, conflict-free) ----
  bf16x8 zr0[16], zr1[16];
  {
    const int xr = l31 * 16;
    const int rb0 = (wr * 64 + l31) * 512;
    const int rb1 = (wr * 64 + 32 + l31) * 512;
    const int hx = hi * 16;
#pragma unroll
    for (int ks = 0; ks < 16; ++ks) {
      zr0[ks] = *(const bf16x8*)(lds + rb0 + ((ks * 32 + hx) ^ xr));
      zr1[ks] = *(const bf16x8*)(lds + rb1 + ((ks * 32 + hx) ^ xr));
    }
  }
  asm volatile("s_waitcnt lgkmcnt(0)" ::: "memory");
  __builtin_amdgcn_s_barrier();
  __builtin_amdgcn_sched_barrier(0);

  // ---- cb staging setup; prologue stages g=0,1,2 of half0/ct0 ----
  unsigned char* lcb = lds + tid * 16;
  const char* cgc = (const char*)cbt +
      ((size_t)(tid >> 7) * 131072 + (size_t)chunk * 32768 + (tid & 127) * 16);
  gll16(cgc + 0 * 262144, lcb + 0 * 4096);
  gll16(cgc + 1 * 262144, lcb + 1 * 4096);
  gll16(cgc + 2 * 262144, lcb + 2 * 4096);

  const unsigned char* afp = lds + hi * 2048 + (wc * 64 + l31) * 16;
  const unsigned wchi4 = (unsigned)(wc * 64 + hi * 4);

  unsigned k1_00 = 0xFFFFFFFFu, k2_00 = 0xFFFFFFFFu;
  unsigned k1_01 = 0xFFFFFFFFu, k2_01 = 0xFFFFFFFFu;
  unsigned k1_10 = 0xFFFFFFFFu, k2_10 = 0xFFFFFFFFu;
  unsigned k1_11 = 0xFFFFFFFFu, k2_11 = 0xFFFFFFFFu;
  f32x16 acc00, acc01, acc10, acc11;

#define KSTEP(ks, TAIL)                                                        \
  {                                                                            \
    if ((TAIL) && (ks) == 14) asm volatile("s_waitcnt vmcnt(1)" ::: "memory"); \
    else if ((TAIL) && (ks) == 15) asm volatile("s_waitcnt vmcnt(0)" ::: "memory"); \
    else asm volatile("s_waitcnt vmcnt(2)" ::: "memory");                      \
    __builtin_amdgcn_s_barrier();                                              \
    __builtin_amdgcn_sched_barrier(0);                                         \
    if ((ks) < 13) {                                                           \
      gll16(cgc + ((ks) + 3) * 262144, lcb + (((ks) + 3) & 3) * 4096);         \
    } else if (!(TAIL)) {                                                      \
      gll16(cgc + 2048 + ((ks) - 13) * 262144, lcb + (((ks) + 3) & 3) * 4096); \
    }                                                                          \
    bf16x8 a0 = *(const bf16x8*)(afp + ((ks) & 3) * 4096);                     \
    bf16x8 a1 = *(const bf16x8*)(afp + ((ks) & 3) * 4096 + 512);               \
    acc00 = __builtin_amdgcn_mfma_f32_32x32x16_bf16(a0, zr0[ks], acc00, 0, 0, 0); \
    acc01 = __builtin_amdgcn_mfma_f32_32x32x16_bf16(a0, zr1[ks], acc01, 0, 0, 0); \
    acc10 = __builtin_amdgcn_mfma_f32_32x32x16_bf16(a1, zr0[ks], acc10, 0, 0, 0); \
    acc11 = __builtin_amdgcn_mfma_f32_32x32x16_bf16(a1, zr1[ks], acc11, 0, 0, 0); \
  }

// branchless top-2 merge: exact same result as the if-chain (keys unique)
#define MRG(K1V, K2V, KEY)                                                     \
  {                                                                            \
    unsigned t_ = umax32(K1V, (KEY));                                          \
    K2V = umin32(K2V, t_);                                                     \
    K1V = umin32(K1V, (KEY));                                                  \
  }

#define CTBODY(HALF, TAIL)                                                     \
  {                                                                            \
    const int cnoff = 65536 + (HALF) * 4096 + ct * 512 + wc * 256 + hi * 16;   \
    f32x4 cnA[4], cnB[4];                                                      \
    _Pragma("unroll") for (int g2 = 0; g2 < 4; ++g2) {                         \
      cnA[g2] = *(const f32x4*)(lds + cnoff + g2 * 32);                        \
      cnB[g2] = *(const f32x4*)(lds + cnoff + 128 + g2 * 32);                  \
    }                                                                          \
    _Pragma("unroll") for (int r = 0; r < 16; ++r) {                           \
      float vA = cnA[r >> 2][r & 3], vB = cnB[r >> 2][r & 3];                  \
      acc00[r] = vA; acc01[r] = vA; acc10[r] = vB; acc11[r] = vB;              \
    }                                                                          \
    KSTEP(0, TAIL)  KSTEP(1, TAIL)  KSTEP(2, TAIL)  KSTEP(3, TAIL)             \
    KSTEP(4, TAIL)  KSTEP(5, TAIL)  KSTEP(6, TAIL)  KSTEP(7, TAIL)             \
    KSTEP(8, TAIL)  KSTEP(9, TAIL)  KSTEP(10, TAIL) KSTEP(11, TAIL)            \
    KSTEP(12, TAIL) KSTEP(13, TAIL) KSTEP(14, TAIL) KSTEP(15, TAIL)            \
    const unsigned vb = (unsigned)(ct * 128) | wchi4;                          \
    _Pragma("unroll") for (int r = 0; r < 16; ++r) {                           \
      const unsigned base = (unsigned)(8 * (r >> 2) + (r & 3));                \
      unsigned key;                                                            \
      key = (__float_as_uint(acc00[r]) & 0xFFFFFC00u) | (vb | base);           \
      MRG(k1_00, k2_00, key)                                                   \
      key = (__float_as_uint(acc01[r]) & 0xFFFFFC00u) | (vb | base);           \
      MRG(k1_01, k2_01, key)                                                   \
      key = (__float_as_uint(acc10[r]) & 0xFFFFFC00u) | (vb | base | 32u);     \
      MRG(k1_10, k2_10, key)                                                   \
      key = (__float_as_uint(acc11[r]) & 0xFFFFFC00u) | (vb | base | 32u);     \
      MRG(k1_11, k2_11, key)                                                   \
    }                                                                          \
    cgc += 2048;                                                               \
  }

  // ---- half 0: codes [chunk*2048, +1024) ----
  for (int ct = 0; ct < 8; ++ct) CTBODY(0, false)
  unsigned s1_00 = k1_00, s2_00 = k2_00, s1_01 = k1_01, s2_01 = k2_01;
  unsigned s1_10 = k1_10, s2_10 = k2_10, s1_11 = k1_11, s2_11 = k2_11;
  k1_00 = k2_00 = k1_01 = k2_01 = 0xFFFFFFFFu;
  k1_10 = k2_10 = k1_11 = k2_11 = 0xFFFFFFFFu;

  // ---- half 1: codes [chunk*2048+1024, +1024) ----
  for (int ct = 0; ct < 7; ++ct) CTBODY(1, false)
  { int ct = 7; CTBODY(1, true) }
#undef CTBODY
#undef MRG
#undef KSTEP

  // ---- epilogue: merge lane <-> lane+32, store per-(zf,cf,half) top-2 ----
#define FIN(K1V, K2V, ZF, ENT)                                                 \
  {                                                                            \
    unsigned o1 = (unsigned)__shfl_xor((int)(K1V), 32);                        \
    unsigned o2 = (unsigned)__shfl_xor((int)(K2V), 32);                        \
    unsigned n1 = umin32((K1V), o1);                                           \
    unsigned n2 = umin32(umax32((K1V), o1), umin32((K2V), o2));                \
    if (lane < 32) {                                                           \
      int row = r0 + wr * 64 + (ZF) * 32 + l31;                                \
      partials[(size_t)row * 32 + (ENT)] =                                     \
          ((unsigned long long)n2 << 32) | n1;                                 \
    }                                                                          \
  }
  const int eb = chunk * 8 + wc * 2;
  FIN(s1_00, s2_00, 0, eb + 0) FIN(s1_10, s2_10, 0, eb + 1)
  FIN(s1_01, s2_01, 1, eb + 0) FIN(s1_11, s2_11, 1, eb + 1)
  FIN(k1_00, k2_00, 0, eb + 4) FIN(k1_10, k2_10, 0, eb + 5)
  FIN(k1_01, k2_01, 1, eb + 4) FIN(k1_11, k2_11, 1, eb + 5)
#undef FIN
}

// ---- merge partials (wave/row) + refine + histogram + fused zq/loss ----
__global__ __launch_bounds__(256) void k_reduce(
    const unsigned long long* __restrict__ partials, const float* __restrict__ z,
    const float* __restrict__ cb, float* __restrict__ out_codes,
    int* __restrict__ cnt, float* __restrict__ zq,
    float* __restrict__ loss_part) {
  const int row = blockIdx.x * 4 + (threadIdx.x >> 6);
  const int lane = threadIdx.x & 63;
  const int e = lane & 31;

  unsigned myK1 = 0xFFFFFFFFu, myK2 = 0xFFFFFFFFu;
  if (lane < 32) {
    unsigned long long v = partials[(size_t)row * 32 + e];
    myK1 = (unsigned)v; myK2 = (unsigned)(v >> 32);
  }
  unsigned K1 = myK1, K2 = myK2;
  int bc = e >> 2;   // 1024-code chunk of K1
#pragma unroll
  for (int m = 1; m <= 32; m <<= 1) {
    unsigned o1 = (unsigned)__shfl_xor((int)K1, m);
    unsigned o2 = (unsigned)__shfl_xor((int)K2, m);
    int ob = __shfl_xor(bc, m);
    unsigned nK2 = umin32(umax32(K1, o1), umin32(K2, o2));
    if (o1 < K1 || (o1 == K1 && ob < bc)) { K1 = o1; bc = ob; }
    K2 = nK2;
  }
  int chosen = bc * 1024 + (int)(K1 & 1023u);

  const float* zr = z + ((size_t)row << 8);
  float r1 = __uint_as_float(K1 & 0xFFFFFC00u);
  float r2 = __uint_as_float(K2 & 0xFFFFFC00u);
  if (r2 - r1 < 0.75f) {   // wave-uniform near-tie: exact fp64 re-eval
    const float win = r1 + 0.75f;
    double bestd = 1e300; int bestj = 0x7fffffff;
#pragma unroll
    for (int h = 0; h < 2; ++h) {
      unsigned k = h ? myK2 : myK1;
      float bv = __uint_as_float(k & 0xFFFFFC00u);
      if (lane < 32 && bv <= win) {
        int jv = (e >> 2) * 1024 + (int)(k & 1023u);
        const float* c = cb + ((size_t)jv << 8);
        double d = 0.0;
        for (int kk = 0; kk < DIM; ++kk) {
          double df = (double)zr[kk] - (double)c[kk];
          d += df * df;
        }
        if (d < bestd || (d == bestd && jv < bestj)) { bestd = d; bestj = jv; }
      }
    }
#pragma unroll
    for (int m = 1; m <= 32; m <<= 1) {
      double od = __shfl_xor(bestd, m);
      int oj = __shfl_xor(bestj, m);
      if (od < bestd || (od == bestd && oj < bestj)) { bestd = od; bestj = oj; }
    }
    chosen = bestj;
  }
  if (lane == 0) {
    out_codes[row] = (float)chosen;
    if (cnt) atomicAdd(&cnt[chosen], 1);
  }

  // fused straight-through output + commitment loss (sorted path only)
  if (zq) {
    const float* cq = cb + ((size_t)chosen << 8);
    float4 zv = ((const float4*)zr)[lane];
    float4 qv = ((const float4*)cq)[lane];
    ((float4*)(zq + ((size_t)row << 8)))[lane] = qv;
    float d0 = zv.x - qv.x, d1 = zv.y - qv.y;
    float d2 = zv.z - qv.z, d3 = zv.w - qv.w;
    float lacc = (d0 * d0 + d1 * d1) + (d2 * d2 + d3 * d3);
#pragma unroll
    for (int off = 32; off >= 1; off >>= 1) lacc += __shfl_down(lacc, off);
    __shared__ float wls[4];
    if (lane == 0) wls[threadIdx.x >> 6] = lacc;
    __syncthreads();
    if (threadIdx.x == 0) {
      float s = (wls[0] + wls[1]) + (wls[2] + wls[3]);
      atomicAdd(loss_part + (blockIdx.x & 255), s * (float)(0.1 / 4194304.0));
    }
  }
}

// ---- scan (1 block): prefix + cs EMA + cursors + loss finalize -----------
__global__ __launch_bounds__(1024) void k_scan(
    const int* __restrict__ cnt, int* __restrict__ start,
    int* __restrict__ cursor, const float* __restrict__ ema_cs,
    float* __restrict__ cs_out, const float* __restrict__ loss_part,
    float* __restrict__ loss) {
  __shared__ int wsum[16], wbase[16];
  __shared__ float lsum[4];
  const int t = threadIdx.x;
  const int lane = t & 63, wid = t >> 6;
  const int base = t * 8;
  int c[8], s = 0;
#pragma unroll
  for (int i = 0; i < 8; ++i) { c[i] = cnt[base + i]; s += c[i]; }
  int inc = s;
#pragma unroll
  for (int off = 1; off < 64; off <<= 1) {
    int v = __shfl_up(inc, off);
    if (lane >= off) inc += v;
  }
  if (lane == 63) wsum[wid] = inc;
  // loss finalize runs on waves 0-3 (threads 0-255) alongside the scan
  if (t < 256) {
    float ls = loss_part[t];
#pragma unroll
    for (int off = 32; off >= 1; off >>= 1) ls += __shfl_down(ls, off);
    if (lane == 0) lsum[wid] = ls;
  }
  __syncthreads();
  if (t < 16) {
    int v = wsum[t];
    int winc = v;
#pragma unroll
    for (int off = 1; off < 16; off <<= 1) {
      int u = __shfl_up(winc, off);
      if (t >= off) winc += u;
    }
    wbase[t] = winc - v;
  }
  if (t == 16) loss[0] = (lsum[0] + lsum[1]) + (lsum[2] + lsum[3]);
  __syncthreads();
  int ex = wbase[wid] + (inc - s);
#pragma unroll
  for (int i = 0; i < 8; ++i) {
    start[base + i] = ex;
    cursor[base + i] = ex;
    cs_out[base + i] = 0.99f * ema_cs[base + i] + 0.01f * (float)c[i];
    ex += c[i];
  }
}

__global__ __launch_bounds__(256) void k_place(const float* __restrict__ codesf,
                                               int* __restrict__ cursor,
                                               int* __restrict__ rowlist) {
  int i = blockIdx.x * 256 + threadIdx.x;
  int c = (int)codesf[i];
  int p = atomicAdd(&cursor[c], 1);
  rowlist[p] = i;
}

// per-code pass: dw sum + EMA + codebook divide (no zq/loss -- in k_reduce)
__global__ __launch_bounds__(256) void k_dw2(
    const float* __restrict__ z, const int* __restrict__ start,
    const int* __restrict__ cnt, const int* __restrict__ rowlist,
    const float* __restrict__ ema_w, const float* __restrict__ cs_new,
    float* __restrict__ ew, float* __restrict__ cb_out) {
  const int k = blockIdx.x;
  const int d = threadIdx.x;
  const int s = start[k], n = cnt[k];
  const size_t o = ((size_t)k << 8) + d;
  float a0 = 0.f, a1 = 0.f, a2 = 0.f, a3 = 0.f;
  int t = 0;
  for (; t + 4 <= n; t += 4) {
    size_t ro0 = ((size_t)rowlist[s + t] << 8) + d;
    size_t ro1 = ((size_t)rowlist[s + t + 1] << 8) + d;
    size_t ro2 = ((size_t)rowlist[s + t + 2] << 8) + d;
    size_t ro3 = ((size_t)rowlist[s + t + 3] << 8) + d;
    a0 += z[ro0]; a1 += z[ro1]; a2 += z[ro2]; a3 += z[ro3];
  }
  for (; t < n; ++t)
    a0 += z[((size_t)rowlist[s + t] << 8) + d];
  float a = (a0 + a1) + (a2 + a3);
  const float v = 0.99f * ema_w[o] + 0.01f * a;
  ew[o] = v;
  cb_out[o] = v / (cs_new[k] + 1e-5f);
}

// ---------------- fallback atomic path (ws too small) ---------------------
__global__ __launch_bounds__(256) void k_scatter(
    const float* __restrict__ z, const float* __restrict__ cb,
    const float* __restrict__ codesf, float* __restrict__ zq,
    float* __restrict__ loss, float* __restrict__ cs_acc,
    float* __restrict__ ew_acc) {
  const int row = blockIdx.x;
  const int d = threadIdx.x;
  const int c = (int)codesf[row];
  const float zv = z[((size_t)row << 8) + d];
  const float qv = cb[((size_t)c << 8) + d];
  zq[((size_t)row << 8) + d] = zv + (qv - zv);
  float diff = zv - qv;
  float sq = diff * diff;
#pragma unroll
  for (int off = 32; off >= 1; off >>= 1) sq += __shfl_down(sq, off);
  __shared__ float wpart[4];
  if ((d & 63) == 0) wpart[d >> 6] = sq;
  __syncthreads();
  if (d == 0) {
    float s = (wpart[0] + wpart[1]) + (wpart[2] + wpart[3]);
    atomicAdd(loss, s * (float)(0.1 / 4194304.0));
    atomicAdd(cs_acc + c, 1.0f);
  }
  atomicAdd(ew_acc + ((size_t)c << 8) + d, zv);
}

__global__ __launch_bounds__(256) void k_ema_cs(const float* __restrict__ ema_cs,
                                                float* __restrict__ cs_io) {
  const int k = blockIdx.x * 256 + threadIdx.x;
  const float cnt = cs_io[k];
  cs_io[k] = 0.99f * ema_cs[k] + 0.01f * cnt;
}

__global__ __launch_bounds__(256) void k_ema_w(const float* __restrict__ ema_w,
                                               const float* __restrict__ cs_new,
                                               float* __restrict__ ew_io,
                                               float* __restrict__ cb_out) {
  const int i = blockIdx.x * 256 + threadIdx.x;
  const float dw = ew_io[i];
  const float v = 0.99f * ema_w[i] + 0.01f * dw;
  ew_io[i] = v;
  cb_out[i] = v / (cs_new[i >> 8] + 1e-5f);
}

// ---------------- launch --------------------------------------------------
extern "C" void kernel_launch(void* const* d_in, const int* in_sizes, int n_in,
                              void* d_out, int out_size, void* d_ws, size_t ws_size,
                              hipStream_t stream) {
  const float* z      = (const float*)d_in[0];
  const float* cb     = (const float*)d_in[1];
  const float* ema_cs = (const float*)d_in[2];
  const float* ema_w  = (const float*)d_in[3];
  float* out = (float*)d_out;

  float* o_zq    = out + OFF_ZQ;
  float* o_codes = out + OFF_CODES;
  float* o_loss  = out + OFF_LOSS;
  float* o_cb    = out + OFF_CB;
  float* o_cs    = out + OFF_CS;
  float* o_ew    = out + OFF_EW;

  // scratch aliases (each overwritten later in pipeline order):
  //   z_bf16 (8.39MB)               -> o_cb region (k_dw2 cb_out overwrites)
  //   cbt (4.19MB) + partials (4MB) -> o_ew region (k_dw2 ew overwrites)
  //   cnorm (32KB)                  -> d_ws tail; reused as cursor after argmin
  uintptr_t zb_a  = ((uintptr_t)o_cb + 15) & ~(uintptr_t)15;
  uintptr_t cbt_a = ((uintptr_t)o_ew + 15) & ~(uintptr_t)15;
  unsigned short* zbuf = (unsigned short*)zb_a;
  unsigned short* cbt  = (unsigned short*)cbt_a;

  const size_t ws_need = 4 * (8192 * 2 + 16384 + 256 + 8192);  // 164864 B
  const bool sorted = (ws_size >= ws_need);
  int* cnt      = (int*)d_ws;
  int* start    = cnt + 8192;
  int* rowlist  = start + 8192;
  float* loss_part = (float*)(rowlist + 16384);
  float* cnorm_ws  = loss_part + 256;

  float* cnorm;
  unsigned long long* partials;
  if (sorted) {
    cnorm    = cnorm_ws;
    partials = (unsigned long long*)(cbt_a + 4194304);  // behind cbt in o_ew
  } else {
    cnorm    = (float*)(cbt_a + 4194304);
    partials = (unsigned long long*)o_zq;               // k_scatter writes zq
  }

  k_pre<<<3105, 256, 0, stream>>>(z, zbuf, cb, cbt, cnorm,
                                  sorted ? cnt : (int*)nullptr, loss_part);

  dim3 g(4, 128);
  k_argmin<<<g, 256, 0, stream>>>(zbuf, cbt, cnorm, partials);
  k_reduce<<<N_ROWS / 4, 256, 0, stream>>>(
      partials, z, cb, o_codes, sorted ? cnt : (int*)nullptr,
      sorted ? o_zq : (float*)nullptr, loss_part);

  if (sorted) {
    int* cursor = (int*)cnorm_ws;   // cnorm dead after k_argmin
    k_scan <<<1, 1024, 0, stream>>>(cnt, start, cursor, ema_cs, o_cs,
                                    loss_part, o_loss);
    k_place<<<64, 256, 0, stream>>>(o_codes, cursor, rowlist);
    k_dw2<<<KCODES, 256, 0, stream>>>(z, start, cnt, rowlist, ema_w, o_cs,
                                      o_ew, o_cb);
  } else {
    (void)hipMemsetAsync(o_loss, 0,
                         (size_t)(OUT_TOTAL - OFF_LOSS) * sizeof(float), stream);
    k_scatter<<<N_ROWS, 256, 0, stream>>>(z, cb, o_codes, o_zq, o_loss, o_cs,
                                          o_ew);
    k_ema_cs<<<KCODES / 256, 256, 0, stream>>>(ema_cs, o_cs);
    k_ema_w <<<KCODES * DIM / 256, 256, 0, stream>>>(ema_w, o_cs, o_ew, o_cb);
  }
}